// Round 20
// baseline (198.376 us; speedup 1.0000x reference)
//
#include <hip/hip_runtime.h>

#define B_ 128
#define N_ 64
#define T_ 1000
#define H_ 16

typedef float v2f __attribute__((ext_vector_type(2)));
typedef v2f uv2f __attribute__((aligned(4)));

// ---------------- A: energy[b,i] = var(x[b,0,i,:], ddof=1) ----------------
__global__ __launch_bounds__(256) void k_energy(const float* __restrict__ x, float* __restrict__ energy) {
    int row = blockIdx.x;                       // b*64 + i
    const float* xr = x + (size_t)row * T_;
    float s = 0.f, s2 = 0.f;
    for (int t4 = threadIdx.x; t4 < 250; t4 += 256) {
        float4 v = ((const float4*)xr)[t4];
        s += v.x + v.y + v.z + v.w;
        s2 += v.x*v.x + v.y*v.y + v.z*v.z + v.w*v.w;
    }
    __shared__ float r1[256], r2[256];
    r1[threadIdx.x] = s; r2[threadIdx.x] = s2;
    __syncthreads();
    for (int off = 128; off > 0; off >>= 1) {
        if (threadIdx.x < off) {
            r1[threadIdx.x] += r1[threadIdx.x + off];
            r2[threadIdx.x] += r2[threadIdx.x + off];
        }
        __syncthreads();
    }
    if (threadIdx.x == 0) {
        float S = r1[0], S2 = r2[0];
        energy[row] = (S2 - S * S / (float)T_) / (float)(T_ - 1);
    }
}

// ------- C (+attn fused): rank-1 attention softmax in-block, then z_gcn ----
#define ZTC 128
__global__ __launch_bounds__(256) void k_zgcn(const float* __restrict__ energy,
        const float* __restrict__ q_w, const float* __restrict__ q_b,
        const float* __restrict__ k_w, const float* __restrict__ k_b,
        const float* __restrict__ x, float* __restrict__ zg,
        float* __restrict__ wmat_out, double* __restrict__ stats) {
    int b = blockIdx.y;
    int t0 = blockIdx.x * ZTC;
    int tid = threadIdx.x;
    if (blockIdx.x == 0 && b == 0 && tid < 163) stats[tid] = 0.0;
    __shared__ __attribute__((aligned(16))) float wsh[64 * 64];
    __shared__ __attribute__((aligned(16))) float xs[64][ZTC];
    __shared__ float en[64];
    float (*red1)[4] = (float(*)[4])&xs[0][0];   // scratch overlay (pre-staging)
    float (*red2)[4] = (float(*)[4])&xs[2][0];
    if (tid < 64) en[tid] = energy[b * 64 + tid];
    __syncthreads();
    float alpha = 0.f, beta = 0.f;
    #pragma unroll
    for (int hh = 0; hh < H_; ++hh) {
        alpha = fmaf(q_w[hh], k_w[hh], alpha);
        beta  = fmaf(q_b[hh], k_w[hh], beta);
    }
    int row = tid >> 2, q = tid & 3;
    float si = 0.25f * fmaf(alpha, en[row], beta);
    float vals[16];
    float m = -3.0e38f;
    #pragma unroll
    for (int k = 0; k < 16; ++k) {
        int j = q * 16 + k;
        float a = si * en[j];
        if (j == row) a = -3.0e38f;
        vals[k] = a;
        m = fmaxf(m, a);
    }
    red1[row][q] = m;
    __syncthreads();
    float m4 = fmaxf(fmaxf(red1[row][0], red1[row][1]), fmaxf(red1[row][2], red1[row][3]));
    float sum = 0.f;
    #pragma unroll
    for (int k = 0; k < 16; ++k) {
        float p = __expf(vals[k] - m4);
        vals[k] = p;
        sum += p;
    }
    red2[row][q] = sum;
    __syncthreads();
    float den = red2[row][0] + red2[row][1] + red2[row][2] + red2[row][3];
    float inv = 1.f / den;
    #pragma unroll
    for (int k = 0; k < 16; ++k) vals[k] *= inv;
    __syncthreads();                             // red scratch dead before xs staging
    #pragma unroll
    for (int k = 0; k < 16; ++k) wsh[row * 64 + q * 16 + k] = vals[k];
    if (blockIdx.x == 0) {
        float* wr = wmat_out + (size_t)b * 4096 + row * 64 + q * 16;
        ((float4*)wr)[0] = float4{vals[0],  vals[1],  vals[2],  vals[3]};
        ((float4*)wr)[1] = float4{vals[4],  vals[5],  vals[6],  vals[7]};
        ((float4*)wr)[2] = float4{vals[8],  vals[9],  vals[10], vals[11]};
        ((float4*)wr)[3] = float4{vals[12], vals[13], vals[14], vals[15]};
    }
    const float* xb = x + (size_t)b * 64 * T_;
    for (int i = tid; i < 2048; i += 256) {
        int jj = i >> 5;
        int c4 = i & 31;
        int tt = t0 + c4 * 4;
        float4 val;
        if (tt + 3 < T_) val = *(const float4*)(xb + jj * T_ + tt);
        else {
            val.x = (tt     < T_) ? xb[jj * T_ + tt]     : 0.f;
            val.y = (tt + 1 < T_) ? xb[jj * T_ + tt + 1] : 0.f;
            val.z = (tt + 2 < T_) ? xb[jj * T_ + tt + 2] : 0.f;
            val.w = (tt + 3 < T_) ? xb[jj * T_ + tt + 3] : 0.f;
        }
        *(float4*)&xs[jj][c4 * 4] = val;
    }
    __syncthreads();
    int gi = tid >> 5, gt = tid & 31;
    int ii0 = gi * 8, tt0 = gt * 4;
    float4 acc[8];
    #pragma unroll
    for (int r = 0; r < 8; ++r) acc[r] = float4{0.f, 0.f, 0.f, 0.f};
    for (int jj = 0; jj < 64; ++jj) {
        float4 xv = *(const float4*)&xs[jj][tt0];
        #pragma unroll
        for (int r = 0; r < 8; ++r) {
            float wv = wsh[(ii0 + r) * 64 + jj];
            acc[r].x += wv * xv.x; acc[r].y += wv * xv.y;
            acc[r].z += wv * xv.z; acc[r].w += wv * xv.w;
        }
    }
    int tt = t0 + tt0;
    #pragma unroll
    for (int r = 0; r < 8; ++r) {
        float4 res = *(const float4*)&xs[ii0 + r][tt0];
        acc[r].x += res.x; acc[r].y += res.y; acc[r].z += res.z; acc[r].w += res.w;
        float* dst = zg + (size_t)b * 64 * T_ + (size_t)(ii0 + r) * T_;
        if (tt + 3 < T_) {
            *(float4*)(dst + tt) = acc[r];
        } else {
            if (tt     < T_) dst[tt]     = acc[r].x;
            if (tt + 1 < T_) dst[tt + 1] = acc[r].y;
            if (tt + 2 < T_) dst[tt + 2] = acc[r].z;
            if (tt + 3 < T_) dst[tt + 3] = acc[r].w;
        }
    }
}

// ------- D: autocorr lags 0..14 + total sum + boundary corrections ---------
__global__ __launch_bounds__(256) void k_autocorr(const float* __restrict__ zg, double* __restrict__ stats) {
    __shared__ float rows[8][1070];             // stride-33 spans, conflict-free
    int row0 = blockIdx.x * 8;
    for (int idx = threadIdx.x; idx < 8 * 1070; idx += 256) {
        int rr = idx / 1070, j = idx - rr * 1070;
        rows[rr][j] = (j < T_) ? zg[(size_t)(row0 + rr) * T_ + j] : 0.f;
    }
    __syncthreads();
    int r = threadIdx.x >> 5, q = threadIdx.x & 31;
    const float* p = &rows[r][0];
    int t = q * 33;
    float w0=p[t+0], w1=p[t+1], w2=p[t+2], w3=p[t+3], w4=p[t+4], w5=p[t+5], w6=p[t+6],
          w7=p[t+7], w8=p[t+8], w9=p[t+9], w10=p[t+10], w11=p[t+11], w12=p[t+12], w13=p[t+13], w14;
    float a0=0.f,a1=0.f,a2=0.f,a3=0.f,a4=0.f,a5=0.f,a6=0.f,a7=0.f,a8=0.f,a9=0.f,
          a10=0.f,a11=0.f,a12=0.f,a13=0.f,a14=0.f, s1=0.f;
    #define ASTEP(wA,wB,wC,wD,wE,wF,wG,wH,wI,wJ,wK,wL,wM,wN,wO, off) { \
        wO = p[t + (off) + 14]; \
        s1 += wA; \
        a0  = fmaf(wA,wA,a0);  a1  = fmaf(wA,wB,a1);  a2  = fmaf(wA,wC,a2);  \
        a3  = fmaf(wA,wD,a3);  a4  = fmaf(wA,wE,a4);  a5  = fmaf(wA,wF,a5);  \
        a6  = fmaf(wA,wG,a6);  a7  = fmaf(wA,wH,a7);  a8  = fmaf(wA,wI,a8);  \
        a9  = fmaf(wA,wJ,a9);  a10 = fmaf(wA,wK,a10); a11 = fmaf(wA,wL,a11); \
        a12 = fmaf(wA,wM,a12); a13 = fmaf(wA,wN,a13); a14 = fmaf(wA,wO,a14); }
    #define AR0(o)  ASTEP(w0,w1,w2,w3,w4,w5,w6,w7,w8,w9,w10,w11,w12,w13,w14, o)
    #define AR1(o)  ASTEP(w1,w2,w3,w4,w5,w6,w7,w8,w9,w10,w11,w12,w13,w14,w0, o)
    #define AR2(o)  ASTEP(w2,w3,w4,w5,w6,w7,w8,w9,w10,w11,w12,w13,w14,w0,w1, o)
    #define AR3(o)  ASTEP(w3,w4,w5,w6,w7,w8,w9,w10,w11,w12,w13,w14,w0,w1,w2, o)
    #define AR4(o)  ASTEP(w4,w5,w6,w7,w8,w9,w10,w11,w12,w13,w14,w0,w1,w2,w3, o)
    #define AR5(o)  ASTEP(w5,w6,w7,w8,w9,w10,w11,w12,w13,w14,w0,w1,w2,w3,w4, o)
    #define AR6(o)  ASTEP(w6,w7,w8,w9,w10,w11,w12,w13,w14,w0,w1,w2,w3,w4,w5, o)
    #define AR7(o)  ASTEP(w7,w8,w9,w10,w11,w12,w13,w14,w0,w1,w2,w3,w4,w5,w6, o)
    #define AR8(o)  ASTEP(w8,w9,w10,w11,w12,w13,w14,w0,w1,w2,w3,w4,w5,w6,w7, o)
    #define AR9(o)  ASTEP(w9,w10,w11,w12,w13,w14,w0,w1,w2,w3,w4,w5,w6,w7,w8, o)
    #define AR10(o) ASTEP(w10,w11,w12,w13,w14,w0,w1,w2,w3,w4,w5,w6,w7,w8,w9, o)
    #define AR11(o) ASTEP(w11,w12,w13,w14,w0,w1,w2,w3,w4,w5,w6,w7,w8,w9,w10, o)
    #define AR12(o) ASTEP(w12,w13,w14,w0,w1,w2,w3,w4,w5,w6,w7,w8,w9,w10,w11, o)
    #define AR13(o) ASTEP(w13,w14,w0,w1,w2,w3,w4,w5,w6,w7,w8,w9,w10,w11,w12, o)
    #define AR14(o) ASTEP(w14,w0,w1,w2,w3,w4,w5,w6,w7,w8,w9,w10,w11,w12,w13, o)
    for (int mi = 0; mi < 2; ++mi) {
        AR0(0) AR1(1) AR2(2) AR3(3) AR4(4) AR5(5) AR6(6) AR7(7)
        AR8(8) AR9(9) AR10(10) AR11(11) AR12(12) AR13(13) AR14(14)
        t += 15;
    }
    AR0(0) AR1(1) AR2(2)                        // 33 total
    #undef ASTEP
    __syncthreads();
    float eacc = 0.f;
    int v = threadIdx.x;
    if (v < 147) {
        int mode, ia, ib;
        if (v < 105) { mode = 0; ia = v / 15; ib = ia + (v % 15); }
        else if (v < 133) {
            int idx = v - 105; int i = 0, len = 7;
            while (idx >= len) { idx -= len; ++i; --len; }
            mode = 2; ia = 993 + i; ib = 993 + i + idx;
        }
        else if (v < 140) { mode = 1; ia = 0; ib = v - 133; }
        else { mode = 1; ia = 993 + (v - 140); ib = 999; }
        for (int rr = 0; rr < 8; ++rr) {
            const float* zr = &rows[rr][0];
            float val;
            if (mode != 1) val = zr[ia] * zr[ib];
            else { val = 0.f; for (int i = ia; i <= ib; ++i) val += zr[i]; }
            eacc += val;
        }
    }
    __syncthreads();
    float* red = &rows[0][0];
    int tid = threadIdx.x;
    red[tid*17+0]=a0;  red[tid*17+1]=a1;  red[tid*17+2]=a2;  red[tid*17+3]=a3;
    red[tid*17+4]=a4;  red[tid*17+5]=a5;  red[tid*17+6]=a6;  red[tid*17+7]=a7;
    red[tid*17+8]=a8;  red[tid*17+9]=a9;  red[tid*17+10]=a10; red[tid*17+11]=a11;
    red[tid*17+12]=a12; red[tid*17+13]=a13; red[tid*17+14]=a14; red[tid*17+15]=s1;
    __syncthreads();
    for (int off = 128; off > 0; off >>= 1) {
        if (tid < off)
            for (int k = 0; k < 16; ++k) red[tid*17+k] += red[(tid+off)*17+k];
        __syncthreads();
    }
    if (tid < 16) atomicAdd(&stats[tid], (double)red[tid]);
    if (v < 147) atomicAdd(&stats[16 + v], (double)eacc);
}

// ---------------- E: finalize BN -> folded taps + shift --------------------
__global__ void k_finalize2(const double* __restrict__ stats, const float* __restrict__ conv_w,
                            const float* __restrict__ gamma, const float* __restrict__ beta,
                            float* __restrict__ scsh) {
    int h = threadIdx.x;
    if (h >= 16) return;
    const double M = (double)(B_ * N_) * (double)T_;
    double w[15];
    for (int k = 0; k < 15; ++k) w[k] = (double)conv_w[h * 15 + k];
    double SA = stats[15];
    const double* HP  = stats + 16;
    const double* TP  = stats + 16 + 105;
    const double* PRE = stats + 16 + 133;
    const double* SUF = stats + 16 + 140;
    double so = 0.0;
    for (int k = 0; k < 15; ++k) {
        double U = SA;
        if (k < 7)      U -= SUF[k];
        else if (k > 7) U -= PRE[k - 8];
        so += w[k] * U;
    }
    double mean_o = so / M;
    double q = 0.0;
    for (int k = 0; k < 15; ++k)
    for (int k2 = 0; k2 < 15; ++k2) {
        int a = (k < k2) ? k : k2;
        int d = (k < k2) ? (k2 - k) : (k - k2);
        double G = stats[d];
        if (a >= 8)
            for (int i = 0; i <= a - 8; ++i) G -= HP[i * 15 + d];
        if (a + d <= 6)
            for (int i = a + 993; i <= 999 - d; ++i) {
                int ip = i - 993;
                G -= TP[ip * 7 - ip * (ip - 1) / 2 + d];
            }
        q += w[k] * w[k2] * G;
    }
    double var = q / M - mean_o * mean_o;
    double sc = (double)gamma[h] / sqrt(var + 1e-5);
    scsh[240 + h] = (float)((double)beta[h] - mean_o * sc);
    for (int k = 0; k < 15; ++k) scsh[h * 15 + k] = (float)(w[k] * sc);
}

// ------- F: conv via packed v_pk_fma_f32 pairs + ELU + serial LIF ----------
// 16 rows x 16 ch per block; T in 21 chunks of 48 (last 40).
// Output pair (2m,2m+1): even taps use E_j=(p[2j],p[2j+1]), odd taps O_j=(p[2j+1],p[2j+2]).
__global__ __launch_bounds__(256, 2) void k_scan(const float* __restrict__ zg,
        const float* __restrict__ scsh, float* __restrict__ zfeat) {
    __shared__ float in_s[2][16][68];
    int tid = threadIdx.x;
    int h = tid & 15, r = tid >> 4;
    int row0 = blockIdx.x * 16;
    float c0 = scsh[h*15+0],  c1 = scsh[h*15+1],  c2 = scsh[h*15+2],  c3 = scsh[h*15+3];
    float c4 = scsh[h*15+4],  c5 = scsh[h*15+5],  c6 = scsh[h*15+6],  c7 = scsh[h*15+7];
    float c8 = scsh[h*15+8],  c9 = scsh[h*15+9],  c10 = scsh[h*15+10], c11 = scsh[h*15+11];
    float c12 = scsh[h*15+12], c13 = scsh[h*15+13], c14 = scsh[h*15+14];
    float sh = scsh[240 + h];
    v2f cb0 = {c0,c0},  cb1 = {c1,c1},  cb2 = {c2,c2},  cb3 = {c3,c3},  cb4 = {c4,c4};
    v2f cb5 = {c5,c5},  cb6 = {c6,c6},  cb7 = {c7,c7},  cb8 = {c8,c8},  cb9 = {c9,c9};
    v2f cb10 = {c10,c10}, cb11 = {c11,c11}, cb12 = {c12,c12}, cb13 = {c13,c13}, cb14 = {c14,c14};
    v2f shp = {sh, sh}, zzp = {0.f, 0.f};
    float u = 2.f, cnt = 0.f;
    float ld0, ld1, ld2, ld3;
    int su = tid & 63, sr = tid >> 6;

    #define STAGE_LOAD(cc) { \
        int g = (cc) * 48 - 7 + su; \
        bool ok = (g >= 0 && g < T_); \
        const float* zp_ = zg + (size_t)(row0 + sr) * T_ + g; \
        ld0 = ok ? zp_[0] : 0.f; \
        ld1 = ok ? zp_[4 * T_] : 0.f; \
        ld2 = ok ? zp_[8 * T_] : 0.f; \
        ld3 = ok ? zp_[12 * T_] : 0.f; }

    #define STAGE_WRITE(db) { \
        in_s[db][sr][su]      = ld0; \
        in_s[db][sr + 4][su]  = ld1; \
        in_s[db][sr + 8][su]  = ld2; \
        in_s[db][sr + 12][su] = ld3; }

    #define PK_FMA(acc, c, xp) asm("v_pk_fma_f32 %0, %1, %2, %0" : "+v"(acc) : "v"(c), "v"(xp))
    #define PK_ADD(d, a, b)    asm("v_pk_add_f32 %0, %1, %2" : "=v"(d) : "v"(a), "v"(b))

    #define LIF1(aa) { \
        u = fmaf(0.5f, u, aa); \
        float sp = (u > 2.5f) ? 1.f : 0.f; \
        cnt += sp; u = fmaf(-0.5f, sp, u); }

    #define PAIR(Ea,Eb,Ec,Ed,Ee,Ef,Eg,Eh, Oa,Ob,Oc,Od,Oe,Of,Og) { \
        v2f aE = shp, aO = zzp; \
        PK_FMA(aE, cb0,  Ea); PK_FMA(aO, cb1,  Oa); \
        PK_FMA(aE, cb2,  Eb); PK_FMA(aO, cb3,  Ob); \
        PK_FMA(aE, cb4,  Ec); PK_FMA(aO, cb5,  Oc); \
        PK_FMA(aE, cb6,  Ed); PK_FMA(aO, cb7,  Od); \
        PK_FMA(aE, cb8,  Ee); PK_FMA(aO, cb9,  Oe); \
        PK_FMA(aE, cb10, Ef); PK_FMA(aO, cb11, Of); \
        PK_FMA(aE, cb12, Eg); PK_FMA(aO, cb13, Og); \
        PK_FMA(aE, cb14, Eh); \
        v2f zp; PK_ADD(zp, aE, aO); \
        float pe0 = fmaxf(zp.x, 0.f) + __expf(fminf(zp.x, 0.f)); \
        float pe1 = fmaxf(zp.y, 0.f) + __expf(fminf(zp.y, 0.f)); \
        LIF1(pe0) LIF1(pe1) }

    #define LD2(i) (*(const uv2f*)(p + (i)))
    #define LOADWIN \
        v2f E0=LD2(0),  E1=LD2(2),  E2=LD2(4),  E3=LD2(6),  E4=LD2(8),  E5=LD2(10), E6=LD2(12), E7=LD2(14), \
            E8=LD2(16), E9=LD2(18), E10=LD2(20), E11=LD2(22), E12=LD2(24), E13=LD2(26), E14=LD2(28), E15=LD2(30), \
            E16=LD2(32), E17=LD2(34), E18=LD2(36), E19=LD2(38), E20=LD2(40), E21=LD2(42), E22=LD2(44), E23=LD2(46), \
            E24=LD2(48), E25=LD2(50), E26=LD2(52), E27=LD2(54), E28=LD2(56), E29=LD2(58), E30=LD2(60); \
        v2f O0=LD2(1),  O1=LD2(3),  O2=LD2(5),  O3=LD2(7),  O4=LD2(9),  O5=LD2(11), O6=LD2(13), O7=LD2(15), \
            O8=LD2(17), O9=LD2(19), O10=LD2(21), O11=LD2(23), O12=LD2(25), O13=LD2(27), O14=LD2(29), O15=LD2(31), \
            O16=LD2(33), O17=LD2(35), O18=LD2(37), O19=LD2(39), O20=LD2(41), O21=LD2(43), O22=LD2(45), O23=LD2(47), \
            O24=LD2(49), O25=LD2(51), O26=LD2(53), O27=LD2(55), O28=LD2(57), O29=LD2(59);

    #define PAIRS20 \
        PAIR(E0,E1,E2,E3,E4,E5,E6,E7,       O0,O1,O2,O3,O4,O5,O6) \
        PAIR(E1,E2,E3,E4,E5,E6,E7,E8,       O1,O2,O3,O4,O5,O6,O7) \
        PAIR(E2,E3,E4,E5,E6,E7,E8,E9,       O2,O3,O4,O5,O6,O7,O8) \
        PAIR(E3,E4,E5,E6,E7,E8,E9,E10,      O3,O4,O5,O6,O7,O8,O9) \
        PAIR(E4,E5,E6,E7,E8,E9,E10,E11,     O4,O5,O6,O7,O8,O9,O10) \
        PAIR(E5,E6,E7,E8,E9,E10,E11,E12,    O5,O6,O7,O8,O9,O10,O11) \
        PAIR(E6,E7,E8,E9,E10,E11,E12,E13,   O6,O7,O8,O9,O10,O11,O12) \
        PAIR(E7,E8,E9,E10,E11,E12,E13,E14,  O7,O8,O9,O10,O11,O12,O13) \
        PAIR(E8,E9,E10,E11,E12,E13,E14,E15, O8,O9,O10,O11,O12,O13,O14) \
        PAIR(E9,E10,E11,E12,E13,E14,E15,E16, O9,O10,O11,O12,O13,O14,O15) \
        PAIR(E10,E11,E12,E13,E14,E15,E16,E17, O10,O11,O12,O13,O14,O15,O16) \
        PAIR(E11,E12,E13,E14,E15,E16,E17,E18, O11,O12,O13,O14,O15,O16,O17) \
        PAIR(E12,E13,E14,E15,E16,E17,E18,E19, O12,O13,O14,O15,O16,O17,O18) \
        PAIR(E13,E14,E15,E16,E17,E18,E19,E20, O13,O14,O15,O16,O17,O18,O19) \
        PAIR(E14,E15,E16,E17,E18,E19,E20,E21, O14,O15,O16,O17,O18,O19,O20) \
        PAIR(E15,E16,E17,E18,E19,E20,E21,E22, O15,O16,O17,O18,O19,O20,O21) \
        PAIR(E16,E17,E18,E19,E20,E21,E22,E23, O16,O17,O18,O19,O20,O21,O22) \
        PAIR(E17,E18,E19,E20,E21,E22,E23,E24, O17,O18,O19,O20,O21,O22,O23) \
        PAIR(E18,E19,E20,E21,E22,E23,E24,E25, O18,O19,O20,O21,O22,O23,O24) \
        PAIR(E19,E20,E21,E22,E23,E24,E25,E26, O19,O20,O21,O22,O23,O24,O25)

    #define PAIRS_LAST4 \
        PAIR(E20,E21,E22,E23,E24,E25,E26,E27, O20,O21,O22,O23,O24,O25,O26) \
        PAIR(E21,E22,E23,E24,E25,E26,E27,E28, O21,O22,O23,O24,O25,O26,O27) \
        PAIR(E22,E23,E24,E25,E26,E27,E28,E29, O22,O23,O24,O25,O26,O27,O28) \
        PAIR(E23,E24,E25,E26,E27,E28,E29,E30, O23,O24,O25,O26,O27,O28,O29)

    STAGE_LOAD(0)
    STAGE_WRITE(0)
    __syncthreads();
    int buf = 0;
    #pragma unroll 1
    for (int c = 0; c < 20; ++c) {
        STAGE_LOAD(c + 1)                       // issue early (T14)
        {
            const float* p = &in_s[buf][r][0];
            LOADWIN
            PAIRS20
            PAIRS_LAST4
        }
        STAGE_WRITE(buf ^ 1)                    // write late (after compute)
        __syncthreads();
        buf ^= 1;
    }
    {   // tail chunk: 40 outputs = 20 pairs
        const float* p = &in_s[buf][r][0];
        LOADWIN
        PAIRS20
    }
    #undef STAGE_LOAD
    #undef STAGE_WRITE
    #undef PK_FMA
    #undef PK_ADD
    #undef LIF1
    #undef PAIR
    #undef LD2
    #undef LOADWIN
    #undef PAIRS20
    #undef PAIRS_LAST4
    int row = row0 + r;
    int b = row >> 6, i = row & 63;
    zfeat[(size_t)b * 1024 + h * 64 + i] = cnt * (1.0f / (float)T_);
}

// ---------------- G: logits = z_feat @ fc_w.T + fc_b -----------------------
__global__ __launch_bounds__(256) void k_fc(const float* __restrict__ zfeat, const float* __restrict__ fc_w,
                     const float* __restrict__ fc_b, float* __restrict__ logits) {
    int b = blockIdx.x;
    const float* zf = zfeat + (size_t)b * 1024;
    float a0 = 0.f, a1 = 0.f, a2 = 0.f, a3 = 0.f;
    for (int f = threadIdx.x; f < 1024; f += 256) {
        float z = zf[f];
        a0 += z * fc_w[f];
        a1 += z * fc_w[1024 + f];
        a2 += z * fc_w[2048 + f];
        a3 += z * fc_w[3072 + f];
    }
    __shared__ float red[4][256];
    red[0][threadIdx.x] = a0; red[1][threadIdx.x] = a1;
    red[2][threadIdx.x] = a2; red[3][threadIdx.x] = a3;
    __syncthreads();
    for (int off = 128; off > 0; off >>= 1) {
        if (threadIdx.x < off) {
            red[0][threadIdx.x] += red[0][threadIdx.x + off];
            red[1][threadIdx.x] += red[1][threadIdx.x + off];
            red[2][threadIdx.x] += red[2][threadIdx.x + off];
            red[3][threadIdx.x] += red[3][threadIdx.x + off];
        }
        __syncthreads();
    }
    if (threadIdx.x < 4) logits[b * 4 + threadIdx.x] = red[threadIdx.x][0] + fc_b[threadIdx.x];
}

extern "C" void kernel_launch(void* const* d_in, const int* in_sizes, int n_in,
                              void* d_out, int out_size, void* d_ws, size_t ws_size,
                              hipStream_t stream) {
    (void)in_sizes; (void)n_in; (void)out_size; (void)ws_size;
    const float* x      = (const float*)d_in[0];
    const float* q_w    = (const float*)d_in[1];
    const float* q_b    = (const float*)d_in[2];
    const float* k_w    = (const float*)d_in[3];
    const float* k_b    = (const float*)d_in[4];
    const float* conv_w = (const float*)d_in[5];
    const float* bn_g   = (const float*)d_in[7];
    const float* bn_b   = (const float*)d_in[8];
    const float* fc_w   = (const float*)d_in[9];
    const float* fc_b   = (const float*)d_in[10];

    float* out    = (float*)d_out;
    float* logits = out;                        // 128*4
    float* zfeat  = out + 512;                  // 128*1024
    float* wmat   = out + 512 + 131072;         // 128*64*64

    char* ws      = (char*)d_ws;
    float* energy = (float*)ws;                               // 32 KB
    float* zg     = (float*)(ws + 32768);                     // 32.768 MB
    double* stats = (double*)(ws + 32768 + 32768000);         // 2 KB
    float* scsh   = (float*)(ws + 32768 + 32768000 + 2048);   // 1 KB

    k_energy<<<B_ * N_, 256, 0, stream>>>(x, energy);
    k_zgcn<<<dim3(8, B_), 256, 0, stream>>>(energy, q_w, q_b, k_w, k_b, x, zg, wmat, stats);
    k_autocorr<<<B_ * N_ / 8, 256, 0, stream>>>(zg, stats);
    k_finalize2<<<1, 64, 0, stream>>>(stats, conv_w, bn_g, bn_b, scsh);
    k_scan<<<B_ * N_ / 16, 256, 0, stream>>>(zg, scsh, zfeat);
    k_fc<<<B_, 256, 0, stream>>>(zfeat, fc_w, fc_b, logits);
}

// Round 21
// 172.433 us; speedup vs baseline: 1.1505x; 1.1505x over previous
//
#include <hip/hip_runtime.h>

#define B_ 128
#define N_ 64
#define T_ 1000
#define H_ 16

typedef float v2f __attribute__((ext_vector_type(2)));
typedef v2f uv2f __attribute__((aligned(4)));

// ---------------- A: energy[b,i] = var(x[b,0,i,:], ddof=1) ----------------
__global__ __launch_bounds__(256) void k_energy(const float* __restrict__ x, float* __restrict__ energy) {
    int row = blockIdx.x;                       // b*64 + i
    const float* xr = x + (size_t)row * T_;
    float s = 0.f, s2 = 0.f;
    for (int t4 = threadIdx.x; t4 < 250; t4 += 256) {
        float4 v = ((const float4*)xr)[t4];
        s += v.x + v.y + v.z + v.w;
        s2 += v.x*v.x + v.y*v.y + v.z*v.z + v.w*v.w;
    }
    __shared__ float r1[256], r2[256];
    r1[threadIdx.x] = s; r2[threadIdx.x] = s2;
    __syncthreads();
    for (int off = 128; off > 0; off >>= 1) {
        if (threadIdx.x < off) {
            r1[threadIdx.x] += r1[threadIdx.x + off];
            r2[threadIdx.x] += r2[threadIdx.x + off];
        }
        __syncthreads();
    }
    if (threadIdx.x == 0) {
        float S = r1[0], S2 = r2[0];
        energy[row] = (S2 - S * S / (float)T_) / (float)(T_ - 1);
    }
}

// ------- C (+attn fused): rank-1 attention softmax in-block, then z_gcn ----
#define ZTC 128
__global__ __launch_bounds__(256) void k_zgcn(const float* __restrict__ energy,
        const float* __restrict__ q_w, const float* __restrict__ q_b,
        const float* __restrict__ k_w, const float* __restrict__ k_b,
        const float* __restrict__ x, float* __restrict__ zg,
        float* __restrict__ wmat_out, double* __restrict__ stats) {
    int b = blockIdx.y;
    int t0 = blockIdx.x * ZTC;
    int tid = threadIdx.x;
    if (blockIdx.x == 0 && b == 0 && tid < 163) stats[tid] = 0.0;
    __shared__ __attribute__((aligned(16))) float wsh[64 * 64];
    __shared__ __attribute__((aligned(16))) float xs[64][ZTC];
    __shared__ float en[64];
    float (*red1)[4] = (float(*)[4])&xs[0][0];   // scratch overlay (pre-staging)
    float (*red2)[4] = (float(*)[4])&xs[2][0];
    if (tid < 64) en[tid] = energy[b * 64 + tid];
    __syncthreads();
    float alpha = 0.f, beta = 0.f;
    #pragma unroll
    for (int hh = 0; hh < H_; ++hh) {
        alpha = fmaf(q_w[hh], k_w[hh], alpha);
        beta  = fmaf(q_b[hh], k_w[hh], beta);
    }
    int row = tid >> 2, q = tid & 3;
    float si = 0.25f * fmaf(alpha, en[row], beta);
    float vals[16];
    float m = -3.0e38f;
    #pragma unroll
    for (int k = 0; k < 16; ++k) {
        int j = q * 16 + k;
        float a = si * en[j];
        if (j == row) a = -3.0e38f;
        vals[k] = a;
        m = fmaxf(m, a);
    }
    red1[row][q] = m;
    __syncthreads();
    float m4 = fmaxf(fmaxf(red1[row][0], red1[row][1]), fmaxf(red1[row][2], red1[row][3]));
    float sum = 0.f;
    #pragma unroll
    for (int k = 0; k < 16; ++k) {
        float p = __expf(vals[k] - m4);
        vals[k] = p;
        sum += p;
    }
    red2[row][q] = sum;
    __syncthreads();
    float den = red2[row][0] + red2[row][1] + red2[row][2] + red2[row][3];
    float inv = 1.f / den;
    #pragma unroll
    for (int k = 0; k < 16; ++k) vals[k] *= inv;
    __syncthreads();                             // red scratch dead before xs staging
    #pragma unroll
    for (int k = 0; k < 16; ++k) wsh[row * 64 + q * 16 + k] = vals[k];
    if (blockIdx.x == 0) {
        float* wr = wmat_out + (size_t)b * 4096 + row * 64 + q * 16;
        ((float4*)wr)[0] = float4{vals[0],  vals[1],  vals[2],  vals[3]};
        ((float4*)wr)[1] = float4{vals[4],  vals[5],  vals[6],  vals[7]};
        ((float4*)wr)[2] = float4{vals[8],  vals[9],  vals[10], vals[11]};
        ((float4*)wr)[3] = float4{vals[12], vals[13], vals[14], vals[15]};
    }
    const float* xb = x + (size_t)b * 64 * T_;
    for (int i = tid; i < 2048; i += 256) {
        int jj = i >> 5;
        int c4 = i & 31;
        int tt = t0 + c4 * 4;
        float4 val;
        if (tt + 3 < T_) val = *(const float4*)(xb + jj * T_ + tt);
        else {
            val.x = (tt     < T_) ? xb[jj * T_ + tt]     : 0.f;
            val.y = (tt + 1 < T_) ? xb[jj * T_ + tt + 1] : 0.f;
            val.z = (tt + 2 < T_) ? xb[jj * T_ + tt + 2] : 0.f;
            val.w = (tt + 3 < T_) ? xb[jj * T_ + tt + 3] : 0.f;
        }
        *(float4*)&xs[jj][c4 * 4] = val;
    }
    __syncthreads();
    int gi = tid >> 5, gt = tid & 31;
    int ii0 = gi * 8, tt0 = gt * 4;
    float4 acc[8];
    #pragma unroll
    for (int r = 0; r < 8; ++r) acc[r] = float4{0.f, 0.f, 0.f, 0.f};
    for (int jj = 0; jj < 64; ++jj) {
        float4 xv = *(const float4*)&xs[jj][tt0];
        #pragma unroll
        for (int r = 0; r < 8; ++r) {
            float wv = wsh[(ii0 + r) * 64 + jj];
            acc[r].x += wv * xv.x; acc[r].y += wv * xv.y;
            acc[r].z += wv * xv.z; acc[r].w += wv * xv.w;
        }
    }
    int tt = t0 + tt0;
    #pragma unroll
    for (int r = 0; r < 8; ++r) {
        float4 res = *(const float4*)&xs[ii0 + r][tt0];
        acc[r].x += res.x; acc[r].y += res.y; acc[r].z += res.z; acc[r].w += res.w;
        float* dst = zg + (size_t)b * 64 * T_ + (size_t)(ii0 + r) * T_;
        if (tt + 3 < T_) {
            *(float4*)(dst + tt) = acc[r];
        } else {
            if (tt     < T_) dst[tt]     = acc[r].x;
            if (tt + 1 < T_) dst[tt + 1] = acc[r].y;
            if (tt + 2 < T_) dst[tt + 2] = acc[r].z;
            if (tt + 3 < T_) dst[tt + 3] = acc[r].w;
        }
    }
}

// ------- D: autocorr lags 0..14 + total sum + boundary corrections ---------
__global__ __launch_bounds__(256) void k_autocorr(const float* __restrict__ zg, double* __restrict__ stats) {
    __shared__ float rows[8][1070];             // stride-33 spans, conflict-free
    int row0 = blockIdx.x * 8;
    for (int idx = threadIdx.x; idx < 8 * 1070; idx += 256) {
        int rr = idx / 1070, j = idx - rr * 1070;
        rows[rr][j] = (j < T_) ? zg[(size_t)(row0 + rr) * T_ + j] : 0.f;
    }
    __syncthreads();
    int r = threadIdx.x >> 5, q = threadIdx.x & 31;
    const float* p = &rows[r][0];
    int t = q * 33;
    float w0=p[t+0], w1=p[t+1], w2=p[t+2], w3=p[t+3], w4=p[t+4], w5=p[t+5], w6=p[t+6],
          w7=p[t+7], w8=p[t+8], w9=p[t+9], w10=p[t+10], w11=p[t+11], w12=p[t+12], w13=p[t+13], w14;
    float a0=0.f,a1=0.f,a2=0.f,a3=0.f,a4=0.f,a5=0.f,a6=0.f,a7=0.f,a8=0.f,a9=0.f,
          a10=0.f,a11=0.f,a12=0.f,a13=0.f,a14=0.f, s1=0.f;
    #define ASTEP(wA,wB,wC,wD,wE,wF,wG,wH,wI,wJ,wK,wL,wM,wN,wO, off) { \
        wO = p[t + (off) + 14]; \
        s1 += wA; \
        a0  = fmaf(wA,wA,a0);  a1  = fmaf(wA,wB,a1);  a2  = fmaf(wA,wC,a2);  \
        a3  = fmaf(wA,wD,a3);  a4  = fmaf(wA,wE,a4);  a5  = fmaf(wA,wF,a5);  \
        a6  = fmaf(wA,wG,a6);  a7  = fmaf(wA,wH,a7);  a8  = fmaf(wA,wI,a8);  \
        a9  = fmaf(wA,wJ,a9);  a10 = fmaf(wA,wK,a10); a11 = fmaf(wA,wL,a11); \
        a12 = fmaf(wA,wM,a12); a13 = fmaf(wA,wN,a13); a14 = fmaf(wA,wO,a14); }
    #define AR0(o)  ASTEP(w0,w1,w2,w3,w4,w5,w6,w7,w8,w9,w10,w11,w12,w13,w14, o)
    #define AR1(o)  ASTEP(w1,w2,w3,w4,w5,w6,w7,w8,w9,w10,w11,w12,w13,w14,w0, o)
    #define AR2(o)  ASTEP(w2,w3,w4,w5,w6,w7,w8,w9,w10,w11,w12,w13,w14,w0,w1, o)
    #define AR3(o)  ASTEP(w3,w4,w5,w6,w7,w8,w9,w10,w11,w12,w13,w14,w0,w1,w2, o)
    #define AR4(o)  ASTEP(w4,w5,w6,w7,w8,w9,w10,w11,w12,w13,w14,w0,w1,w2,w3, o)
    #define AR5(o)  ASTEP(w5,w6,w7,w8,w9,w10,w11,w12,w13,w14,w0,w1,w2,w3,w4, o)
    #define AR6(o)  ASTEP(w6,w7,w8,w9,w10,w11,w12,w13,w14,w0,w1,w2,w3,w4,w5, o)
    #define AR7(o)  ASTEP(w7,w8,w9,w10,w11,w12,w13,w14,w0,w1,w2,w3,w4,w5,w6, o)
    #define AR8(o)  ASTEP(w8,w9,w10,w11,w12,w13,w14,w0,w1,w2,w3,w4,w5,w6,w7, o)
    #define AR9(o)  ASTEP(w9,w10,w11,w12,w13,w14,w0,w1,w2,w3,w4,w5,w6,w7,w8, o)
    #define AR10(o) ASTEP(w10,w11,w12,w13,w14,w0,w1,w2,w3,w4,w5,w6,w7,w8,w9, o)
    #define AR11(o) ASTEP(w11,w12,w13,w14,w0,w1,w2,w3,w4,w5,w6,w7,w8,w9,w10, o)
    #define AR12(o) ASTEP(w12,w13,w14,w0,w1,w2,w3,w4,w5,w6,w7,w8,w9,w10,w11, o)
    #define AR13(o) ASTEP(w13,w14,w0,w1,w2,w3,w4,w5,w6,w7,w8,w9,w10,w11,w12, o)
    #define AR14(o) ASTEP(w14,w0,w1,w2,w3,w4,w5,w6,w7,w8,w9,w10,w11,w12,w13, o)
    for (int mi = 0; mi < 2; ++mi) {
        AR0(0) AR1(1) AR2(2) AR3(3) AR4(4) AR5(5) AR6(6) AR7(7)
        AR8(8) AR9(9) AR10(10) AR11(11) AR12(12) AR13(13) AR14(14)
        t += 15;
    }
    AR0(0) AR1(1) AR2(2)                        // 33 total
    #undef ASTEP
    __syncthreads();
    float eacc = 0.f;
    int v = threadIdx.x;
    if (v < 147) {
        int mode, ia, ib;
        if (v < 105) { mode = 0; ia = v / 15; ib = ia + (v % 15); }
        else if (v < 133) {
            int idx = v - 105; int i = 0, len = 7;
            while (idx >= len) { idx -= len; ++i; --len; }
            mode = 2; ia = 993 + i; ib = 993 + i + idx;
        }
        else if (v < 140) { mode = 1; ia = 0; ib = v - 133; }
        else { mode = 1; ia = 993 + (v - 140); ib = 999; }
        for (int rr = 0; rr < 8; ++rr) {
            const float* zr = &rows[rr][0];
            float val;
            if (mode != 1) val = zr[ia] * zr[ib];
            else { val = 0.f; for (int i = ia; i <= ib; ++i) val += zr[i]; }
            eacc += val;
        }
    }
    __syncthreads();
    float* red = &rows[0][0];
    int tid = threadIdx.x;
    red[tid*17+0]=a0;  red[tid*17+1]=a1;  red[tid*17+2]=a2;  red[tid*17+3]=a3;
    red[tid*17+4]=a4;  red[tid*17+5]=a5;  red[tid*17+6]=a6;  red[tid*17+7]=a7;
    red[tid*17+8]=a8;  red[tid*17+9]=a9;  red[tid*17+10]=a10; red[tid*17+11]=a11;
    red[tid*17+12]=a12; red[tid*17+13]=a13; red[tid*17+14]=a14; red[tid*17+15]=s1;
    __syncthreads();
    for (int off = 128; off > 0; off >>= 1) {
        if (tid < off)
            for (int k = 0; k < 16; ++k) red[tid*17+k] += red[(tid+off)*17+k];
        __syncthreads();
    }
    if (tid < 16) atomicAdd(&stats[tid], (double)red[tid]);
    if (v < 147) atomicAdd(&stats[16 + v], (double)eacc);
}

// ---- E: finalize BN (parallel: 256 threads, stats in LDS) -> folded taps ----
__global__ __launch_bounds__(256) void k_finalize2(const double* __restrict__ stats,
                            const float* __restrict__ conv_w,
                            const float* __restrict__ gamma, const float* __restrict__ beta,
                            float* __restrict__ scsh) {
    __shared__ double sst[163];
    __shared__ double pd[16][16];
    int tid = threadIdx.x;
    if (tid < 163) sst[tid] = stats[tid];
    __syncthreads();
    int h = tid >> 4, j = tid & 15;
    const double SA = sst[15];
    const double* HP  = sst + 16;
    const double* TP  = sst + 16 + 105;
    const double* PRE = sst + 16 + 133;
    const double* SUF = sst + 16 + 140;
    double w[15];
    #pragma unroll
    for (int k = 0; k < 15; ++k) w[k] = (double)conv_w[h * 15 + k];
    double part = 0.0;
    if (j < 15) {                               // k = j slice of the quadratic form
        int k = j;
        #pragma unroll
        for (int k2 = 0; k2 < 15; ++k2) {
            int a = (k < k2) ? k : k2;
            int d = (k < k2) ? (k2 - k) : (k - k2);
            double G = sst[d];
            if (a >= 8)
                for (int i = 0; i <= a - 8; ++i) G -= HP[i * 15 + d];
            if (a + d <= 6)
                for (int i = a + 993; i <= 999 - d; ++i) {
                    int ip = i - 993;
                    G -= TP[ip * 7 - ip * (ip - 1) / 2 + d];
                }
            part += w[k] * w[k2] * G;
        }
    } else {                                    // j == 15: mean numerator
        double so = 0.0;
        #pragma unroll
        for (int k = 0; k < 15; ++k) {
            double U = SA;
            if (k < 7)      U -= SUF[k];
            else if (k > 7) U -= PRE[k - 8];
            so += w[k] * U;
        }
        part = so;
    }
    pd[h][j] = part;
    __syncthreads();
    if (j == 0) {
        const double M = (double)(B_ * N_) * (double)T_;
        double q = 0.0;
        #pragma unroll
        for (int jj = 0; jj < 15; ++jj) q += pd[h][jj];
        double mean_o = pd[h][15] / M;
        double var = q / M - mean_o * mean_o;
        double sc = (double)gamma[h] / sqrt(var + 1e-5);
        scsh[240 + h] = (float)((double)beta[h] - mean_o * sc);
        #pragma unroll
        for (int k = 0; k < 15; ++k) scsh[h * 15 + k] = (float)(w[k] * sc);
    }
}

// ------- F: conv via packed v_pk_fma_f32 pairs + ELU + serial LIF ----------
// 16 rows x 16 ch per block; T in 21 chunks of 48 (last 40).
// Output pair (2m,2m+1): even taps use E_j=(p[2j],p[2j+1]), odd taps O_j=(p[2j+1],p[2j+2]).
__global__ __launch_bounds__(256, 2) void k_scan(const float* __restrict__ zg,
        const float* __restrict__ scsh, float* __restrict__ zfeat) {
    __shared__ float in_s[2][16][68];
    int tid = threadIdx.x;
    int h = tid & 15, r = tid >> 4;
    int row0 = blockIdx.x * 16;
    float c0 = scsh[h*15+0],  c1 = scsh[h*15+1],  c2 = scsh[h*15+2],  c3 = scsh[h*15+3];
    float c4 = scsh[h*15+4],  c5 = scsh[h*15+5],  c6 = scsh[h*15+6],  c7 = scsh[h*15+7];
    float c8 = scsh[h*15+8],  c9 = scsh[h*15+9],  c10 = scsh[h*15+10], c11 = scsh[h*15+11];
    float c12 = scsh[h*15+12], c13 = scsh[h*15+13], c14 = scsh[h*15+14];
    float sh = scsh[240 + h];
    v2f cb0 = {c0,c0},  cb1 = {c1,c1},  cb2 = {c2,c2},  cb3 = {c3,c3},  cb4 = {c4,c4};
    v2f cb5 = {c5,c5},  cb6 = {c6,c6},  cb7 = {c7,c7},  cb8 = {c8,c8},  cb9 = {c9,c9};
    v2f cb10 = {c10,c10}, cb11 = {c11,c11}, cb12 = {c12,c12}, cb13 = {c13,c13}, cb14 = {c14,c14};
    v2f shp = {sh, sh}, zzp = {0.f, 0.f};
    float u = 2.f, cnt = 0.f;
    float ld0, ld1, ld2, ld3;
    int su = tid & 63, sr = tid >> 6;

    #define STAGE_LOAD(cc) { \
        int g = (cc) * 48 - 7 + su; \
        bool ok = (g >= 0 && g < T_); \
        const float* zp_ = zg + (size_t)(row0 + sr) * T_ + g; \
        ld0 = ok ? zp_[0] : 0.f; \
        ld1 = ok ? zp_[4 * T_] : 0.f; \
        ld2 = ok ? zp_[8 * T_] : 0.f; \
        ld3 = ok ? zp_[12 * T_] : 0.f; }

    #define STAGE_WRITE(db) { \
        in_s[db][sr][su]      = ld0; \
        in_s[db][sr + 4][su]  = ld1; \
        in_s[db][sr + 8][su]  = ld2; \
        in_s[db][sr + 12][su] = ld3; }

    #define PK_FMA(acc, c, xp) asm("v_pk_fma_f32 %0, %1, %2, %0" : "+v"(acc) : "v"(c), "v"(xp))
    #define PK_ADD(d, a, b)    asm("v_pk_add_f32 %0, %1, %2" : "=v"(d) : "v"(a), "v"(b))

    #define LIF1(aa) { \
        u = fmaf(0.5f, u, aa); \
        float sp = (u > 2.5f) ? 1.f : 0.f; \
        cnt += sp; u = fmaf(-0.5f, sp, u); }

    #define PAIR(Ea,Eb,Ec,Ed,Ee,Ef,Eg,Eh, Oa,Ob,Oc,Od,Oe,Of,Og) { \
        v2f aE = shp, aO = zzp; \
        PK_FMA(aE, cb0,  Ea); PK_FMA(aO, cb1,  Oa); \
        PK_FMA(aE, cb2,  Eb); PK_FMA(aO, cb3,  Ob); \
        PK_FMA(aE, cb4,  Ec); PK_FMA(aO, cb5,  Oc); \
        PK_FMA(aE, cb6,  Ed); PK_FMA(aO, cb7,  Od); \
        PK_FMA(aE, cb8,  Ee); PK_FMA(aO, cb9,  Oe); \
        PK_FMA(aE, cb10, Ef); PK_FMA(aO, cb11, Of); \
        PK_FMA(aE, cb12, Eg); PK_FMA(aO, cb13, Og); \
        PK_FMA(aE, cb14, Eh); \
        v2f zp; PK_ADD(zp, aE, aO); \
        float pe0 = fmaxf(zp.x, 0.f) + __expf(fminf(zp.x, 0.f)); \
        float pe1 = fmaxf(zp.y, 0.f) + __expf(fminf(zp.y, 0.f)); \
        LIF1(pe0) LIF1(pe1) }

    #define LD2(i) (*(const uv2f*)(p + (i)))
    #define LOADWIN \
        v2f E0=LD2(0),  E1=LD2(2),  E2=LD2(4),  E3=LD2(6),  E4=LD2(8),  E5=LD2(10), E6=LD2(12), E7=LD2(14), \
            E8=LD2(16), E9=LD2(18), E10=LD2(20), E11=LD2(22), E12=LD2(24), E13=LD2(26), E14=LD2(28), E15=LD2(30), \
            E16=LD2(32), E17=LD2(34), E18=LD2(36), E19=LD2(38), E20=LD2(40), E21=LD2(42), E22=LD2(44), E23=LD2(46), \
            E24=LD2(48), E25=LD2(50), E26=LD2(52), E27=LD2(54), E28=LD2(56), E29=LD2(58), E30=LD2(60); \
        v2f O0=LD2(1),  O1=LD2(3),  O2=LD2(5),  O3=LD2(7),  O4=LD2(9),  O5=LD2(11), O6=LD2(13), O7=LD2(15), \
            O8=LD2(17), O9=LD2(19), O10=LD2(21), O11=LD2(23), O12=LD2(25), O13=LD2(27), O14=LD2(29), O15=LD2(31), \
            O16=LD2(33), O17=LD2(35), O18=LD2(37), O19=LD2(39), O20=LD2(41), O21=LD2(43), O22=LD2(45), O23=LD2(47), \
            O24=LD2(49), O25=LD2(51), O26=LD2(53), O27=LD2(55), O28=LD2(57), O29=LD2(59);

    #define PAIRS20 \
        PAIR(E0,E1,E2,E3,E4,E5,E6,E7,       O0,O1,O2,O3,O4,O5,O6) \
        PAIR(E1,E2,E3,E4,E5,E6,E7,E8,       O1,O2,O3,O4,O5,O6,O7) \
        PAIR(E2,E3,E4,E5,E6,E7,E8,E9,       O2,O3,O4,O5,O6,O7,O8) \
        PAIR(E3,E4,E5,E6,E7,E8,E9,E10,      O3,O4,O5,O6,O7,O8,O9) \
        PAIR(E4,E5,E6,E7,E8,E9,E10,E11,     O4,O5,O6,O7,O8,O9,O10) \
        PAIR(E5,E6,E7,E8,E9,E10,E11,E12,    O5,O6,O7,O8,O9,O10,O11) \
        PAIR(E6,E7,E8,E9,E10,E11,E12,E13,   O6,O7,O8,O9,O10,O11,O12) \
        PAIR(E7,E8,E9,E10,E11,E12,E13,E14,  O7,O8,O9,O10,O11,O12,O13) \
        PAIR(E8,E9,E10,E11,E12,E13,E14,E15, O8,O9,O10,O11,O12,O13,O14) \
        PAIR(E9,E10,E11,E12,E13,E14,E15,E16, O9,O10,O11,O12,O13,O14,O15) \
        PAIR(E10,E11,E12,E13,E14,E15,E16,E17, O10,O11,O12,O13,O14,O15,O16) \
        PAIR(E11,E12,E13,E14,E15,E16,E17,E18, O11,O12,O13,O14,O15,O16,O17) \
        PAIR(E12,E13,E14,E15,E16,E17,E18,E19, O12,O13,O14,O15,O16,O17,O18) \
        PAIR(E13,E14,E15,E16,E17,E18,E19,E20, O13,O14,O15,O16,O17,O18,O19) \
        PAIR(E14,E15,E16,E17,E18,E19,E20,E21, O14,O15,O16,O17,O18,O19,O20) \
        PAIR(E15,E16,E17,E18,E19,E20,E21,E22, O15,O16,O17,O18,O19,O20,O21) \
        PAIR(E16,E17,E18,E19,E20,E21,E22,E23, O16,O17,O18,O19,O20,O21,O22) \
        PAIR(E17,E18,E19,E20,E21,E22,E23,E24, O17,O18,O19,O20,O21,O22,O23) \
        PAIR(E18,E19,E20,E21,E22,E23,E24,E25, O18,O19,O20,O21,O22,O23,O24) \
        PAIR(E19,E20,E21,E22,E23,E24,E25,E26, O19,O20,O21,O22,O23,O24,O25)

    #define PAIRS_LAST4 \
        PAIR(E20,E21,E22,E23,E24,E25,E26,E27, O20,O21,O22,O23,O24,O25,O26) \
        PAIR(E21,E22,E23,E24,E25,E26,E27,E28, O21,O22,O23,O24,O25,O26,O27) \
        PAIR(E22,E23,E24,E25,E26,E27,E28,E29, O22,O23,O24,O25,O26,O27,O28) \
        PAIR(E23,E24,E25,E26,E27,E28,E29,E30, O23,O24,O25,O26,O27,O28,O29)

    STAGE_LOAD(0)
    STAGE_WRITE(0)
    __syncthreads();
    int buf = 0;
    #pragma unroll 1
    for (int c = 0; c < 20; ++c) {
        STAGE_LOAD(c + 1)                       // issue early (T14)
        {
            const float* p = &in_s[buf][r][0];
            LOADWIN
            PAIRS20
            PAIRS_LAST4
        }
        STAGE_WRITE(buf ^ 1)                    // write late (after compute)
        __syncthreads();
        buf ^= 1;
    }
    {   // tail chunk: 40 outputs = 20 pairs
        const float* p = &in_s[buf][r][0];
        LOADWIN
        PAIRS20
    }
    #undef STAGE_LOAD
    #undef STAGE_WRITE
    #undef PK_FMA
    #undef PK_ADD
    #undef LIF1
    #undef PAIR
    #undef LD2
    #undef LOADWIN
    #undef PAIRS20
    #undef PAIRS_LAST4
    int row = row0 + r;
    int b = row >> 6, i = row & 63;
    zfeat[(size_t)b * 1024 + h * 64 + i] = cnt * (1.0f / (float)T_);
}

// ---------------- G: logits = z_feat @ fc_w.T + fc_b -----------------------
__global__ __launch_bounds__(256) void k_fc(const float* __restrict__ zfeat, const float* __restrict__ fc_w,
                     const float* __restrict__ fc_b, float* __restrict__ logits) {
    int b = blockIdx.x;
    const float* zf = zfeat + (size_t)b * 1024;
    float a0 = 0.f, a1 = 0.f, a2 = 0.f, a3 = 0.f;
    for (int f = threadIdx.x; f < 1024; f += 256) {
        float z = zf[f];
        a0 += z * fc_w[f];
        a1 += z * fc_w[1024 + f];
        a2 += z * fc_w[2048 + f];
        a3 += z * fc_w[3072 + f];
    }
    __shared__ float red[4][256];
    red[0][threadIdx.x] = a0; red[1][threadIdx.x] = a1;
    red[2][threadIdx.x] = a2; red[3][threadIdx.x] = a3;
    __syncthreads();
    for (int off = 128; off > 0; off >>= 1) {
        if (threadIdx.x < off) {
            red[0][threadIdx.x] += red[0][threadIdx.x + off];
            red[1][threadIdx.x] += red[1][threadIdx.x + off];
            red[2][threadIdx.x] += red[2][threadIdx.x + off];
            red[3][threadIdx.x] += red[3][threadIdx.x + off];
        }
        __syncthreads();
    }
    if (threadIdx.x < 4) logits[b * 4 + threadIdx.x] = red[threadIdx.x][0] + fc_b[threadIdx.x];
}

extern "C" void kernel_launch(void* const* d_in, const int* in_sizes, int n_in,
                              void* d_out, int out_size, void* d_ws, size_t ws_size,
                              hipStream_t stream) {
    (void)in_sizes; (void)n_in; (void)out_size; (void)ws_size;
    const float* x      = (const float*)d_in[0];
    const float* q_w    = (const float*)d_in[1];
    const float* q_b    = (const float*)d_in[2];
    const float* k_w    = (const float*)d_in[3];
    const float* k_b    = (const float*)d_in[4];
    const float* conv_w = (const float*)d_in[5];
    const float* bn_g   = (const float*)d_in[7];
    const float* bn_b   = (const float*)d_in[8];
    const float* fc_w   = (const float*)d_in[9];
    const float* fc_b   = (const float*)d_in[10];

    float* out    = (float*)d_out;
    float* logits = out;                        // 128*4
    float* zfeat  = out + 512;                  // 128*1024
    float* wmat   = out + 512 + 131072;         // 128*64*64

    char* ws      = (char*)d_ws;
    float* energy = (float*)ws;                               // 32 KB
    float* zg     = (float*)(ws + 32768);                     // 32.768 MB
    double* stats = (double*)(ws + 32768 + 32768000);         // 2 KB
    float* scsh   = (float*)(ws + 32768 + 32768000 + 2048);   // 1 KB

    k_energy<<<B_ * N_, 256, 0, stream>>>(x, energy);
    k_zgcn<<<dim3(8, B_), 256, 0, stream>>>(energy, q_w, q_b, k_w, k_b, x, zg, wmat, stats);
    k_autocorr<<<B_ * N_ / 8, 256, 0, stream>>>(zg, stats);
    k_finalize2<<<1, 256, 0, stream>>>(stats, conv_w, bn_g, bn_b, scsh);
    k_scan<<<B_ * N_ / 16, 256, 0, stream>>>(zg, scsh, zfeat);
    k_fc<<<B_, 256, 0, stream>>>(zfeat, fc_w, fc_b, logits);
}

// Round 22
// 170.966 us; speedup vs baseline: 1.1603x; 1.0086x over previous
//
#include <hip/hip_runtime.h>

#define B_ 128
#define N_ 64
#define T_ 1000
#define H_ 16

typedef float v2f __attribute__((ext_vector_type(2)));

// ---------------- A: energy[b,i] = var(x[b,0,i,:], ddof=1) ----------------
__global__ __launch_bounds__(256) void k_energy(const float* __restrict__ x, float* __restrict__ energy) {
    int row = blockIdx.x;                       // b*64 + i
    const float* xr = x + (size_t)row * T_;
    float s = 0.f, s2 = 0.f;
    for (int t4 = threadIdx.x; t4 < 250; t4 += 256) {
        float4 v = ((const float4*)xr)[t4];
        s += v.x + v.y + v.z + v.w;
        s2 += v.x*v.x + v.y*v.y + v.z*v.z + v.w*v.w;
    }
    __shared__ float r1[256], r2[256];
    r1[threadIdx.x] = s; r2[threadIdx.x] = s2;
    __syncthreads();
    for (int off = 128; off > 0; off >>= 1) {
        if (threadIdx.x < off) {
            r1[threadIdx.x] += r1[threadIdx.x + off];
            r2[threadIdx.x] += r2[threadIdx.x + off];
        }
        __syncthreads();
    }
    if (threadIdx.x == 0) {
        float S = r1[0], S2 = r2[0];
        energy[row] = (S2 - S * S / (float)T_) / (float)(T_ - 1);
    }
}

// ------- C (+attn fused): rank-1 attention softmax in-block, then z_gcn ----
#define ZTC 128
__global__ __launch_bounds__(256) void k_zgcn(const float* __restrict__ energy,
        const float* __restrict__ q_w, const float* __restrict__ q_b,
        const float* __restrict__ k_w, const float* __restrict__ k_b,
        const float* __restrict__ x, float* __restrict__ zg,
        float* __restrict__ wmat_out, double* __restrict__ stats) {
    int b = blockIdx.y;
    int t0 = blockIdx.x * ZTC;
    int tid = threadIdx.x;
    if (blockIdx.x == 0 && b == 0 && tid < 163) stats[tid] = 0.0;
    __shared__ __attribute__((aligned(16))) float wsh[64 * 64];
    __shared__ __attribute__((aligned(16))) float xs[64][ZTC];
    __shared__ float en[64];
    float (*red1)[4] = (float(*)[4])&xs[0][0];   // scratch overlay (pre-staging)
    float (*red2)[4] = (float(*)[4])&xs[2][0];
    if (tid < 64) en[tid] = energy[b * 64 + tid];
    __syncthreads();
    float alpha = 0.f, beta = 0.f;
    #pragma unroll
    for (int hh = 0; hh < H_; ++hh) {
        alpha = fmaf(q_w[hh], k_w[hh], alpha);
        beta  = fmaf(q_b[hh], k_w[hh], beta);
    }
    int row = tid >> 2, q = tid & 3;
    float si = 0.25f * fmaf(alpha, en[row], beta);
    float vals[16];
    float m = -3.0e38f;
    #pragma unroll
    for (int k = 0; k < 16; ++k) {
        int j = q * 16 + k;
        float a = si * en[j];
        if (j == row) a = -3.0e38f;
        vals[k] = a;
        m = fmaxf(m, a);
    }
    red1[row][q] = m;
    __syncthreads();
    float m4 = fmaxf(fmaxf(red1[row][0], red1[row][1]), fmaxf(red1[row][2], red1[row][3]));
    float sum = 0.f;
    #pragma unroll
    for (int k = 0; k < 16; ++k) {
        float p = __expf(vals[k] - m4);
        vals[k] = p;
        sum += p;
    }
    red2[row][q] = sum;
    __syncthreads();
    float den = red2[row][0] + red2[row][1] + red2[row][2] + red2[row][3];
    float inv = 1.f / den;
    #pragma unroll
    for (int k = 0; k < 16; ++k) vals[k] *= inv;
    __syncthreads();                             // red scratch dead before xs staging
    #pragma unroll
    for (int k = 0; k < 16; ++k) wsh[row * 64 + q * 16 + k] = vals[k];
    if (blockIdx.x == 0) {
        float* wr = wmat_out + (size_t)b * 4096 + row * 64 + q * 16;
        ((float4*)wr)[0] = float4{vals[0],  vals[1],  vals[2],  vals[3]};
        ((float4*)wr)[1] = float4{vals[4],  vals[5],  vals[6],  vals[7]};
        ((float4*)wr)[2] = float4{vals[8],  vals[9],  vals[10], vals[11]};
        ((float4*)wr)[3] = float4{vals[12], vals[13], vals[14], vals[15]};
    }
    const float* xb = x + (size_t)b * 64 * T_;
    for (int i = tid; i < 2048; i += 256) {
        int jj = i >> 5;
        int c4 = i & 31;
        int tt = t0 + c4 * 4;
        float4 val;
        if (tt + 3 < T_) val = *(const float4*)(xb + jj * T_ + tt);
        else {
            val.x = (tt     < T_) ? xb[jj * T_ + tt]     : 0.f;
            val.y = (tt + 1 < T_) ? xb[jj * T_ + tt + 1] : 0.f;
            val.z = (tt + 2 < T_) ? xb[jj * T_ + tt + 2] : 0.f;
            val.w = (tt + 3 < T_) ? xb[jj * T_ + tt + 3] : 0.f;
        }
        *(float4*)&xs[jj][c4 * 4] = val;
    }
    __syncthreads();
    int gi = tid >> 5, gt = tid & 31;
    int ii0 = gi * 8, tt0 = gt * 4;
    float4 acc[8];
    #pragma unroll
    for (int r = 0; r < 8; ++r) acc[r] = float4{0.f, 0.f, 0.f, 0.f};
    for (int jj = 0; jj < 64; ++jj) {
        float4 xv = *(const float4*)&xs[jj][tt0];
        #pragma unroll
        for (int r = 0; r < 8; ++r) {
            float wv = wsh[(ii0 + r) * 64 + jj];
            acc[r].x += wv * xv.x; acc[r].y += wv * xv.y;
            acc[r].z += wv * xv.z; acc[r].w += wv * xv.w;
        }
    }
    int tt = t0 + tt0;
    #pragma unroll
    for (int r = 0; r < 8; ++r) {
        float4 res = *(const float4*)&xs[ii0 + r][tt0];
        acc[r].x += res.x; acc[r].y += res.y; acc[r].z += res.z; acc[r].w += res.w;
        float* dst = zg + (size_t)b * 64 * T_ + (size_t)(ii0 + r) * T_;
        if (tt + 3 < T_) {
            *(float4*)(dst + tt) = acc[r];
        } else {
            if (tt     < T_) dst[tt]     = acc[r].x;
            if (tt + 1 < T_) dst[tt + 1] = acc[r].y;
            if (tt + 2 < T_) dst[tt + 2] = acc[r].z;
            if (tt + 3 < T_) dst[tt + 3] = acc[r].w;
        }
    }
}

// ------- D: autocorr lags 0..14 + total sum + boundary corrections ---------
__global__ __launch_bounds__(256) void k_autocorr(const float* __restrict__ zg, double* __restrict__ stats) {
    __shared__ float rows[8][1070];             // stride-33 spans, conflict-free
    int row0 = blockIdx.x * 8;
    for (int idx = threadIdx.x; idx < 8 * 1070; idx += 256) {
        int rr = idx / 1070, j = idx - rr * 1070;
        rows[rr][j] = (j < T_) ? zg[(size_t)(row0 + rr) * T_ + j] : 0.f;
    }
    __syncthreads();
    int r = threadIdx.x >> 5, q = threadIdx.x & 31;
    const float* p = &rows[r][0];
    int t = q * 33;
    float w0=p[t+0], w1=p[t+1], w2=p[t+2], w3=p[t+3], w4=p[t+4], w5=p[t+5], w6=p[t+6],
          w7=p[t+7], w8=p[t+8], w9=p[t+9], w10=p[t+10], w11=p[t+11], w12=p[t+12], w13=p[t+13], w14;
    float a0=0.f,a1=0.f,a2=0.f,a3=0.f,a4=0.f,a5=0.f,a6=0.f,a7=0.f,a8=0.f,a9=0.f,
          a10=0.f,a11=0.f,a12=0.f,a13=0.f,a14=0.f, s1=0.f;
    #define ASTEP(wA,wB,wC,wD,wE,wF,wG,wH,wI,wJ,wK,wL,wM,wN,wO, off) { \
        wO = p[t + (off) + 14]; \
        s1 += wA; \
        a0  = fmaf(wA,wA,a0);  a1  = fmaf(wA,wB,a1);  a2  = fmaf(wA,wC,a2);  \
        a3  = fmaf(wA,wD,a3);  a4  = fmaf(wA,wE,a4);  a5  = fmaf(wA,wF,a5);  \
        a6  = fmaf(wA,wG,a6);  a7  = fmaf(wA,wH,a7);  a8  = fmaf(wA,wI,a8);  \
        a9  = fmaf(wA,wJ,a9);  a10 = fmaf(wA,wK,a10); a11 = fmaf(wA,wL,a11); \
        a12 = fmaf(wA,wM,a12); a13 = fmaf(wA,wN,a13); a14 = fmaf(wA,wO,a14); }
    #define AR0(o)  ASTEP(w0,w1,w2,w3,w4,w5,w6,w7,w8,w9,w10,w11,w12,w13,w14, o)
    #define AR1(o)  ASTEP(w1,w2,w3,w4,w5,w6,w7,w8,w9,w10,w11,w12,w13,w14,w0, o)
    #define AR2(o)  ASTEP(w2,w3,w4,w5,w6,w7,w8,w9,w10,w11,w12,w13,w14,w0,w1, o)
    #define AR3(o)  ASTEP(w3,w4,w5,w6,w7,w8,w9,w10,w11,w12,w13,w14,w0,w1,w2, o)
    #define AR4(o)  ASTEP(w4,w5,w6,w7,w8,w9,w10,w11,w12,w13,w14,w0,w1,w2,w3, o)
    #define AR5(o)  ASTEP(w5,w6,w7,w8,w9,w10,w11,w12,w13,w14,w0,w1,w2,w3,w4, o)
    #define AR6(o)  ASTEP(w6,w7,w8,w9,w10,w11,w12,w13,w14,w0,w1,w2,w3,w4,w5, o)
    #define AR7(o)  ASTEP(w7,w8,w9,w10,w11,w12,w13,w14,w0,w1,w2,w3,w4,w5,w6, o)
    #define AR8(o)  ASTEP(w8,w9,w10,w11,w12,w13,w14,w0,w1,w2,w3,w4,w5,w6,w7, o)
    #define AR9(o)  ASTEP(w9,w10,w11,w12,w13,w14,w0,w1,w2,w3,w4,w5,w6,w7,w8, o)
    #define AR10(o) ASTEP(w10,w11,w12,w13,w14,w0,w1,w2,w3,w4,w5,w6,w7,w8,w9, o)
    #define AR11(o) ASTEP(w11,w12,w13,w14,w0,w1,w2,w3,w4,w5,w6,w7,w8,w9,w10, o)
    #define AR12(o) ASTEP(w12,w13,w14,w0,w1,w2,w3,w4,w5,w6,w7,w8,w9,w10,w11, o)
    #define AR13(o) ASTEP(w13,w14,w0,w1,w2,w3,w4,w5,w6,w7,w8,w9,w10,w11,w12, o)
    #define AR14(o) ASTEP(w14,w0,w1,w2,w3,w4,w5,w6,w7,w8,w9,w10,w11,w12,w13, o)
    for (int mi = 0; mi < 2; ++mi) {
        AR0(0) AR1(1) AR2(2) AR3(3) AR4(4) AR5(5) AR6(6) AR7(7)
        AR8(8) AR9(9) AR10(10) AR11(11) AR12(12) AR13(13) AR14(14)
        t += 15;
    }
    AR0(0) AR1(1) AR2(2)                        // 33 total
    #undef ASTEP
    __syncthreads();
    float eacc = 0.f;
    int v = threadIdx.x;
    if (v < 147) {
        int mode, ia, ib;
        if (v < 105) { mode = 0; ia = v / 15; ib = ia + (v % 15); }
        else if (v < 133) {
            int idx = v - 105; int i = 0, len = 7;
            while (idx >= len) { idx -= len; ++i; --len; }
            mode = 2; ia = 993 + i; ib = 993 + i + idx;
        }
        else if (v < 140) { mode = 1; ia = 0; ib = v - 133; }
        else { mode = 1; ia = 993 + (v - 140); ib = 999; }
        for (int rr = 0; rr < 8; ++rr) {
            const float* zr = &rows[rr][0];
            float val;
            if (mode != 1) val = zr[ia] * zr[ib];
            else { val = 0.f; for (int i = ia; i <= ib; ++i) val += zr[i]; }
            eacc += val;
        }
    }
    __syncthreads();
    float* red = &rows[0][0];
    int tid = threadIdx.x;
    red[tid*17+0]=a0;  red[tid*17+1]=a1;  red[tid*17+2]=a2;  red[tid*17+3]=a3;
    red[tid*17+4]=a4;  red[tid*17+5]=a5;  red[tid*17+6]=a6;  red[tid*17+7]=a7;
    red[tid*17+8]=a8;  red[tid*17+9]=a9;  red[tid*17+10]=a10; red[tid*17+11]=a11;
    red[tid*17+12]=a12; red[tid*17+13]=a13; red[tid*17+14]=a14; red[tid*17+15]=s1;
    __syncthreads();
    for (int off = 128; off > 0; off >>= 1) {
        if (tid < off)
            for (int k = 0; k < 16; ++k) red[tid*17+k] += red[(tid+off)*17+k];
        __syncthreads();
    }
    if (tid < 16) atomicAdd(&stats[tid], (double)red[tid]);
    if (v < 147) atomicAdd(&stats[16 + v], (double)eacc);
}

// ---- E: finalize BN (parallel: 256 threads, stats in LDS) -> folded taps ----
__global__ __launch_bounds__(256) void k_finalize2(const double* __restrict__ stats,
                            const float* __restrict__ conv_w,
                            const float* __restrict__ gamma, const float* __restrict__ beta,
                            float* __restrict__ scsh) {
    __shared__ double sst[163];
    __shared__ double pd[16][16];
    int tid = threadIdx.x;
    if (tid < 163) sst[tid] = stats[tid];
    __syncthreads();
    int h = tid >> 4, j = tid & 15;
    const double SA = sst[15];
    const double* HP  = sst + 16;
    const double* TP  = sst + 16 + 105;
    const double* PRE = sst + 16 + 133;
    const double* SUF = sst + 16 + 140;
    double w[15];
    #pragma unroll
    for (int k = 0; k < 15; ++k) w[k] = (double)conv_w[h * 15 + k];
    double part = 0.0;
    if (j < 15) {                               // k = j slice of the quadratic form
        int k = j;
        #pragma unroll
        for (int k2 = 0; k2 < 15; ++k2) {
            int a = (k < k2) ? k : k2;
            int d = (k < k2) ? (k2 - k) : (k - k2);
            double G = sst[d];
            if (a >= 8)
                for (int i = 0; i <= a - 8; ++i) G -= HP[i * 15 + d];
            if (a + d <= 6)
                for (int i = a + 993; i <= 999 - d; ++i) {
                    int ip = i - 993;
                    G -= TP[ip * 7 - ip * (ip - 1) / 2 + d];
                }
            part += w[k] * w[k2] * G;
        }
    } else {                                    // j == 15: mean numerator
        double so = 0.0;
        #pragma unroll
        for (int k = 0; k < 15; ++k) {
            double U = SA;
            if (k < 7)      U -= SUF[k];
            else if (k > 7) U -= PRE[k - 8];
            so += w[k] * U;
        }
        part = so;
    }
    pd[h][j] = part;
    __syncthreads();
    if (j == 0) {
        const double M = (double)(B_ * N_) * (double)T_;
        double q = 0.0;
        #pragma unroll
        for (int jj = 0; jj < 15; ++jj) q += pd[h][jj];
        double mean_o = pd[h][15] / M;
        double var = q / M - mean_o * mean_o;
        double sc = (double)gamma[h] / sqrt(var + 1e-5);
        scsh[240 + h] = (float)((double)beta[h] - mean_o * sc);
        #pragma unroll
        for (int k = 0; k < 15; ++k) scsh[h * 15 + k] = (float)(w[k] * sc);
    }
}

// ------- F: conv via packed v_pk_fma_f32 pairs + ELU + serial LIF ----------
// 16 rows x 16 ch per block; T in 21 chunks of 48 (last 40).
// Dual-copy LDS: in_s[j]=z[j], in2[j+1]=z[j] -> ALL tap pairs read as aligned
// ds_read_b64 (E from in_s at 2j, O from in2 at 2j+2).
__global__ __launch_bounds__(256, 2) void k_scan(const float* __restrict__ zg,
        const float* __restrict__ scsh, float* __restrict__ zfeat) {
    __shared__ float in_s[2][16][68];
    __shared__ float in2[2][16][68];
    int tid = threadIdx.x;
    int h = tid & 15, r = tid >> 4;
    int row0 = blockIdx.x * 16;
    float c0 = scsh[h*15+0],  c1 = scsh[h*15+1],  c2 = scsh[h*15+2],  c3 = scsh[h*15+3];
    float c4 = scsh[h*15+4],  c5 = scsh[h*15+5],  c6 = scsh[h*15+6],  c7 = scsh[h*15+7];
    float c8 = scsh[h*15+8],  c9 = scsh[h*15+9],  c10 = scsh[h*15+10], c11 = scsh[h*15+11];
    float c12 = scsh[h*15+12], c13 = scsh[h*15+13], c14 = scsh[h*15+14];
    float sh = scsh[240 + h];
    v2f cb0 = {c0,c0},  cb1 = {c1,c1},  cb2 = {c2,c2},  cb3 = {c3,c3},  cb4 = {c4,c4};
    v2f cb5 = {c5,c5},  cb6 = {c6,c6},  cb7 = {c7,c7},  cb8 = {c8,c8},  cb9 = {c9,c9};
    v2f cb10 = {c10,c10}, cb11 = {c11,c11}, cb12 = {c12,c12}, cb13 = {c13,c13}, cb14 = {c14,c14};
    v2f shp = {sh, sh}, zzp = {0.f, 0.f};
    float u = 2.f, cnt = 0.f;
    float ld0, ld1, ld2, ld3;
    int su = tid & 63, sr = tid >> 6;

    #define STAGE_LOAD(cc) { \
        int g = (cc) * 48 - 7 + su; \
        bool ok = (g >= 0 && g < T_); \
        const float* zp_ = zg + (size_t)(row0 + sr) * T_ + g; \
        ld0 = ok ? zp_[0] : 0.f; \
        ld1 = ok ? zp_[4 * T_] : 0.f; \
        ld2 = ok ? zp_[8 * T_] : 0.f; \
        ld3 = ok ? zp_[12 * T_] : 0.f; }

    #define STAGE_WRITE(db) { \
        in_s[db][sr][su]      = ld0;  in2[db][sr][su + 1]      = ld0; \
        in_s[db][sr + 4][su]  = ld1;  in2[db][sr + 4][su + 1]  = ld1; \
        in_s[db][sr + 8][su]  = ld2;  in2[db][sr + 8][su + 1]  = ld2; \
        in_s[db][sr + 12][su] = ld3;  in2[db][sr + 12][su + 1] = ld3; }

    #define PK_FMA(acc, c, xp) asm("v_pk_fma_f32 %0, %1, %2, %0" : "+v"(acc) : "v"(c), "v"(xp))
    #define PK_ADD(d, a, b)    asm("v_pk_add_f32 %0, %1, %2" : "=v"(d) : "v"(a), "v"(b))

    #define LIF1(aa) { \
        u = fmaf(0.5f, u, aa); \
        float sp = (u > 2.5f) ? 1.f : 0.f; \
        cnt += sp; u = fmaf(-0.5f, sp, u); }

    #define PAIR(Ea,Eb,Ec,Ed,Ee,Ef,Eg,Eh, Oa,Ob,Oc,Od,Oe,Of,Og) { \
        v2f aE = shp, aO = zzp; \
        PK_FMA(aE, cb0,  Ea); PK_FMA(aO, cb1,  Oa); \
        PK_FMA(aE, cb2,  Eb); PK_FMA(aO, cb3,  Ob); \
        PK_FMA(aE, cb4,  Ec); PK_FMA(aO, cb5,  Oc); \
        PK_FMA(aE, cb6,  Ed); PK_FMA(aO, cb7,  Od); \
        PK_FMA(aE, cb8,  Ee); PK_FMA(aO, cb9,  Oe); \
        PK_FMA(aE, cb10, Ef); PK_FMA(aO, cb11, Of); \
        PK_FMA(aE, cb12, Eg); PK_FMA(aO, cb13, Og); \
        PK_FMA(aE, cb14, Eh); \
        v2f zp; PK_ADD(zp, aE, aO); \
        float pe0 = fmaxf(zp.x, 0.f) + __expf(fminf(zp.x, 0.f)); \
        float pe1 = fmaxf(zp.y, 0.f) + __expf(fminf(zp.y, 0.f)); \
        LIF1(pe0) LIF1(pe1) }

    // E_j = (z[2j], z[2j+1]) at in_s offset 2j (8B aligned);
    // O_j = (z[2j+1], z[2j+2]) at in2 offset 2j+2 (8B aligned).
    #define LDE(j) (*(const v2f*)(pN + 2*(j)))
    #define LDO(j) (*(const v2f*)(p2 + 2*(j) + 2))
    #define LOADWIN \
        v2f E0=LDE(0),  E1=LDE(1),  E2=LDE(2),  E3=LDE(3),  E4=LDE(4),  E5=LDE(5),  E6=LDE(6),  E7=LDE(7), \
            E8=LDE(8),  E9=LDE(9),  E10=LDE(10), E11=LDE(11), E12=LDE(12), E13=LDE(13), E14=LDE(14), E15=LDE(15), \
            E16=LDE(16), E17=LDE(17), E18=LDE(18), E19=LDE(19), E20=LDE(20), E21=LDE(21), E22=LDE(22), E23=LDE(23), \
            E24=LDE(24), E25=LDE(25), E26=LDE(26), E27=LDE(27), E28=LDE(28), E29=LDE(29), E30=LDE(30); \
        v2f O0=LDO(0),  O1=LDO(1),  O2=LDO(2),  O3=LDO(3),  O4=LDO(4),  O5=LDO(5),  O6=LDO(6),  O7=LDO(7), \
            O8=LDO(8),  O9=LDO(9),  O10=LDO(10), O11=LDO(11), O12=LDO(12), O13=LDO(13), O14=LDO(14), O15=LDO(15), \
            O16=LDO(16), O17=LDO(17), O18=LDO(18), O19=LDO(19), O20=LDO(20), O21=LDO(21), O22=LDO(22), O23=LDO(23), \
            O24=LDO(24), O25=LDO(25), O26=LDO(26), O27=LDO(27), O28=LDO(28), O29=LDO(29);

    #define PAIRS20 \
        PAIR(E0,E1,E2,E3,E4,E5,E6,E7,       O0,O1,O2,O3,O4,O5,O6) \
        PAIR(E1,E2,E3,E4,E5,E6,E7,E8,       O1,O2,O3,O4,O5,O6,O7) \
        PAIR(E2,E3,E4,E5,E6,E7,E8,E9,       O2,O3,O4,O5,O6,O7,O8) \
        PAIR(E3,E4,E5,E6,E7,E8,E9,E10,      O3,O4,O5,O6,O7,O8,O9) \
        PAIR(E4,E5,E6,E7,E8,E9,E10,E11,     O4,O5,O6,O7,O8,O9,O10) \
        PAIR(E5,E6,E7,E8,E9,E10,E11,E12,    O5,O6,O7,O8,O9,O10,O11) \
        PAIR(E6,E7,E8,E9,E10,E11,E12,E13,   O6,O7,O8,O9,O10,O11,O12) \
        PAIR(E7,E8,E9,E10,E11,E12,E13,E14,  O7,O8,O9,O10,O11,O12,O13) \
        PAIR(E8,E9,E10,E11,E12,E13,E14,E15, O8,O9,O10,O11,O12,O13,O14) \
        PAIR(E9,E10,E11,E12,E13,E14,E15,E16, O9,O10,O11,O12,O13,O14,O15) \
        PAIR(E10,E11,E12,E13,E14,E15,E16,E17, O10,O11,O12,O13,O14,O15,O16) \
        PAIR(E11,E12,E13,E14,E15,E16,E17,E18, O11,O12,O13,O14,O15,O16,O17) \
        PAIR(E12,E13,E14,E15,E16,E17,E18,E19, O12,O13,O14,O15,O16,O17,O18) \
        PAIR(E13,E14,E15,E16,E17,E18,E19,E20, O13,O14,O15,O16,O17,O18,O19) \
        PAIR(E14,E15,E16,E17,E18,E19,E20,E21, O14,O15,O16,O17,O18,O19,O20) \
        PAIR(E15,E16,E17,E18,E19,E20,E21,E22, O15,O16,O17,O18,O19,O20,O21) \
        PAIR(E16,E17,E18,E19,E20,E21,E22,E23, O16,O17,O18,O19,O20,O21,O22) \
        PAIR(E17,E18,E19,E20,E21,E22,E23,E24, O17,O18,O19,O20,O21,O22,O23) \
        PAIR(E18,E19,E20,E21,E22,E23,E24,E25, O18,O19,O20,O21,O22,O23,O24) \
        PAIR(E19,E20,E21,E22,E23,E24,E25,E26, O19,O20,O21,O22,O23,O24,O25)

    #define PAIRS_LAST4 \
        PAIR(E20,E21,E22,E23,E24,E25,E26,E27, O20,O21,O22,O23,O24,O25,O26) \
        PAIR(E21,E22,E23,E24,E25,E26,E27,E28, O21,O22,O23,O24,O25,O26,O27) \
        PAIR(E22,E23,E24,E25,E26,E27,E28,E29, O22,O23,O24,O25,O26,O27,O28) \
        PAIR(E23,E24,E25,E26,E27,E28,E29,E30, O23,O24,O25,O26,O27,O28,O29)

    STAGE_LOAD(0)
    STAGE_WRITE(0)
    __syncthreads();
    int buf = 0;
    #pragma unroll 1
    for (int c = 0; c < 20; ++c) {
        STAGE_LOAD(c + 1)                       // issue early (T14)
        {
            const float* pN = &in_s[buf][r][0];
            const float* p2 = &in2[buf][r][0];
            LOADWIN
            PAIRS20
            PAIRS_LAST4
        }
        STAGE_WRITE(buf ^ 1)                    // write late (after compute)
        __syncthreads();
        buf ^= 1;
    }
    {   // tail chunk: 40 outputs = 20 pairs
        const float* pN = &in_s[buf][r][0];
        const float* p2 = &in2[buf][r][0];
        LOADWIN
        PAIRS20
    }
    #undef STAGE_LOAD
    #undef STAGE_WRITE
    #undef PK_FMA
    #undef PK_ADD
    #undef LIF1
    #undef PAIR
    #undef LDE
    #undef LDO
    #undef LOADWIN
    #undef PAIRS20
    #undef PAIRS_LAST4
    int row = row0 + r;
    int b = row >> 6, i = row & 63;
    zfeat[(size_t)b * 1024 + h * 64 + i] = cnt * (1.0f / (float)T_);
}

// ---------------- G: logits = z_feat @ fc_w.T + fc_b -----------------------
__global__ __launch_bounds__(256) void k_fc(const float* __restrict__ zfeat, const float* __restrict__ fc_w,
                     const float* __restrict__ fc_b, float* __restrict__ logits) {
    int b = blockIdx.x;
    const float* zf = zfeat + (size_t)b * 1024;
    float a0 = 0.f, a1 = 0.f, a2 = 0.f, a3 = 0.f;
    for (int f = threadIdx.x; f < 1024; f += 256) {
        float z = zf[f];
        a0 += z * fc_w[f];
        a1 += z * fc_w[1024 + f];
        a2 += z * fc_w[2048 + f];
        a3 += z * fc_w[3072 + f];
    }
    __shared__ float red[4][256];
    red[0][threadIdx.x] = a0; red[1][threadIdx.x] = a1;
    red[2][threadIdx.x] = a2; red[3][threadIdx.x] = a3;
    __syncthreads();
    for (int off = 128; off > 0; off >>= 1) {
        if (threadIdx.x < off) {
            red[0][threadIdx.x] += red[0][threadIdx.x + off];
            red[1][threadIdx.x] += red[1][threadIdx.x + off];
            red[2][threadIdx.x] += red[2][threadIdx.x + off];
            red[3][threadIdx.x] += red[3][threadIdx.x + off];
        }
        __syncthreads();
    }
    if (threadIdx.x < 4) logits[b * 4 + threadIdx.x] = red[threadIdx.x][0] + fc_b[threadIdx.x];
}

extern "C" void kernel_launch(void* const* d_in, const int* in_sizes, int n_in,
                              void* d_out, int out_size, void* d_ws, size_t ws_size,
                              hipStream_t stream) {
    (void)in_sizes; (void)n_in; (void)out_size; (void)ws_size;
    const float* x      = (const float*)d_in[0];
    const float* q_w    = (const float*)d_in[1];
    const float* q_b    = (const float*)d_in[2];
    const float* k_w    = (const float*)d_in[3];
    const float* k_b    = (const float*)d_in[4];
    const float* conv_w = (const float*)d_in[5];
    const float* bn_g   = (const float*)d_in[7];
    const float* bn_b   = (const float*)d_in[8];
    const float* fc_w   = (const float*)d_in[9];
    const float* fc_b   = (const float*)d_in[10];

    float* out    = (float*)d_out;
    float* logits = out;                        // 128*4
    float* zfeat  = out + 512;                  // 128*1024
    float* wmat   = out + 512 + 131072;         // 128*64*64

    char* ws      = (char*)d_ws;
    float* energy = (float*)ws;                               // 32 KB
    float* zg     = (float*)(ws + 32768);                     // 32.768 MB
    double* stats = (double*)(ws + 32768 + 32768000);         // 2 KB
    float* scsh   = (float*)(ws + 32768 + 32768000 + 2048);   // 1 KB

    k_energy<<<B_ * N_, 256, 0, stream>>>(x, energy);
    k_zgcn<<<dim3(8, B_), 256, 0, stream>>>(energy, q_w, q_b, k_w, k_b, x, zg, wmat, stats);
    k_autocorr<<<B_ * N_ / 8, 256, 0, stream>>>(zg, stats);
    k_finalize2<<<1, 256, 0, stream>>>(stats, conv_w, bn_g, bn_b, scsh);
    k_scan<<<B_ * N_ / 16, 256, 0, stream>>>(zg, scsh, zfeat);
    k_fc<<<B_, 256, 0, stream>>>(zfeat, fc_w, fc_b, logits);
}

// Round 23
// 169.758 us; speedup vs baseline: 1.1686x; 1.0071x over previous
//
#include <hip/hip_runtime.h>

#define B_ 128
#define N_ 64
#define T_ 1000
#define H_ 16

typedef float v2f __attribute__((ext_vector_type(2)));

// ---------------- A: energy[b,i] = var(x[b,0,i,:], ddof=1) ----------------
__global__ __launch_bounds__(256) void k_energy(const float* __restrict__ x, float* __restrict__ energy) {
    int row = blockIdx.x;                       // b*64 + i
    const float* xr = x + (size_t)row * T_;
    float s = 0.f, s2 = 0.f;
    for (int t4 = threadIdx.x; t4 < 250; t4 += 256) {
        float4 v = ((const float4*)xr)[t4];
        s += v.x + v.y + v.z + v.w;
        s2 += v.x*v.x + v.y*v.y + v.z*v.z + v.w*v.w;
    }
    __shared__ float r1[256], r2[256];
    r1[threadIdx.x] = s; r2[threadIdx.x] = s2;
    __syncthreads();
    for (int off = 128; off > 0; off >>= 1) {
        if (threadIdx.x < off) {
            r1[threadIdx.x] += r1[threadIdx.x + off];
            r2[threadIdx.x] += r2[threadIdx.x + off];
        }
        __syncthreads();
    }
    if (threadIdx.x == 0) {
        float S = r1[0], S2 = r2[0];
        energy[row] = (S2 - S * S / (float)T_) / (float)(T_ - 1);
    }
}

// ------- C (+attn fused): rank-1 attention softmax in-block, then z_gcn ----
#define ZTC 128
__global__ __launch_bounds__(256) void k_zgcn(const float* __restrict__ energy,
        const float* __restrict__ q_w, const float* __restrict__ q_b,
        const float* __restrict__ k_w, const float* __restrict__ k_b,
        const float* __restrict__ x, float* __restrict__ zg,
        float* __restrict__ wmat_out, double* __restrict__ stats) {
    int b = blockIdx.y;
    int t0 = blockIdx.x * ZTC;
    int tid = threadIdx.x;
    if (blockIdx.x == 0 && b == 0 && tid < 163) stats[tid] = 0.0;
    __shared__ __attribute__((aligned(16))) float wsh[64 * 64];
    __shared__ __attribute__((aligned(16))) float xs[64][ZTC];
    __shared__ float en[64];
    float (*red1)[4] = (float(*)[4])&xs[0][0];   // scratch overlay (pre-staging)
    float (*red2)[4] = (float(*)[4])&xs[2][0];
    if (tid < 64) en[tid] = energy[b * 64 + tid];
    __syncthreads();
    float alpha = 0.f, beta = 0.f;
    #pragma unroll
    for (int hh = 0; hh < H_; ++hh) {
        alpha = fmaf(q_w[hh], k_w[hh], alpha);
        beta  = fmaf(q_b[hh], k_w[hh], beta);
    }
    int row = tid >> 2, q = tid & 3;
    float si = 0.25f * fmaf(alpha, en[row], beta);
    float vals[16];
    float m = -3.0e38f;
    #pragma unroll
    for (int k = 0; k < 16; ++k) {
        int j = q * 16 + k;
        float a = si * en[j];
        if (j == row) a = -3.0e38f;
        vals[k] = a;
        m = fmaxf(m, a);
    }
    red1[row][q] = m;
    __syncthreads();
    float m4 = fmaxf(fmaxf(red1[row][0], red1[row][1]), fmaxf(red1[row][2], red1[row][3]));
    float sum = 0.f;
    #pragma unroll
    for (int k = 0; k < 16; ++k) {
        float p = __expf(vals[k] - m4);
        vals[k] = p;
        sum += p;
    }
    red2[row][q] = sum;
    __syncthreads();
    float den = red2[row][0] + red2[row][1] + red2[row][2] + red2[row][3];
    float inv = 1.f / den;
    #pragma unroll
    for (int k = 0; k < 16; ++k) vals[k] *= inv;
    __syncthreads();                             // red scratch dead before xs staging
    #pragma unroll
    for (int k = 0; k < 16; ++k) wsh[row * 64 + q * 16 + k] = vals[k];
    if (blockIdx.x == 0) {
        float* wr = wmat_out + (size_t)b * 4096 + row * 64 + q * 16;
        ((float4*)wr)[0] = float4{vals[0],  vals[1],  vals[2],  vals[3]};
        ((float4*)wr)[1] = float4{vals[4],  vals[5],  vals[6],  vals[7]};
        ((float4*)wr)[2] = float4{vals[8],  vals[9],  vals[10], vals[11]};
        ((float4*)wr)[3] = float4{vals[12], vals[13], vals[14], vals[15]};
    }
    const float* xb = x + (size_t)b * 64 * T_;
    for (int i = tid; i < 2048; i += 256) {
        int jj = i >> 5;
        int c4 = i & 31;
        int tt = t0 + c4 * 4;
        float4 val;
        if (tt + 3 < T_) val = *(const float4*)(xb + jj * T_ + tt);
        else {
            val.x = (tt     < T_) ? xb[jj * T_ + tt]     : 0.f;
            val.y = (tt + 1 < T_) ? xb[jj * T_ + tt + 1] : 0.f;
            val.z = (tt + 2 < T_) ? xb[jj * T_ + tt + 2] : 0.f;
            val.w = (tt + 3 < T_) ? xb[jj * T_ + tt + 3] : 0.f;
        }
        *(float4*)&xs[jj][c4 * 4] = val;
    }
    __syncthreads();
    int gi = tid >> 5, gt = tid & 31;
    int ii0 = gi * 8, tt0 = gt * 4;
    float4 acc[8];
    #pragma unroll
    for (int r = 0; r < 8; ++r) acc[r] = float4{0.f, 0.f, 0.f, 0.f};
    for (int jj = 0; jj < 64; ++jj) {
        float4 xv = *(const float4*)&xs[jj][tt0];
        #pragma unroll
        for (int r = 0; r < 8; ++r) {
            float wv = wsh[(ii0 + r) * 64 + jj];
            acc[r].x += wv * xv.x; acc[r].y += wv * xv.y;
            acc[r].z += wv * xv.z; acc[r].w += wv * xv.w;
        }
    }
    int tt = t0 + tt0;
    #pragma unroll
    for (int r = 0; r < 8; ++r) {
        float4 res = *(const float4*)&xs[ii0 + r][tt0];
        acc[r].x += res.x; acc[r].y += res.y; acc[r].z += res.z; acc[r].w += res.w;
        float* dst = zg + (size_t)b * 64 * T_ + (size_t)(ii0 + r) * T_;
        if (tt + 3 < T_) {
            *(float4*)(dst + tt) = acc[r];
        } else {
            if (tt     < T_) dst[tt]     = acc[r].x;
            if (tt + 1 < T_) dst[tt + 1] = acc[r].y;
            if (tt + 2 < T_) dst[tt + 2] = acc[r].z;
            if (tt + 3 < T_) dst[tt + 3] = acc[r].w;
        }
    }
}

// ------- D: autocorr lags 0..14 + total sum + boundary corrections ---------
__global__ __launch_bounds__(256) void k_autocorr(const float* __restrict__ zg, double* __restrict__ stats) {
    __shared__ float rows[8][1070];             // stride-33 spans, conflict-free
    int row0 = blockIdx.x * 8;
    for (int idx = threadIdx.x; idx < 8 * 1070; idx += 256) {
        int rr = idx / 1070, j = idx - rr * 1070;
        rows[rr][j] = (j < T_) ? zg[(size_t)(row0 + rr) * T_ + j] : 0.f;
    }
    __syncthreads();
    int r = threadIdx.x >> 5, q = threadIdx.x & 31;
    const float* p = &rows[r][0];
    int t = q * 33;
    float w0=p[t+0], w1=p[t+1], w2=p[t+2], w3=p[t+3], w4=p[t+4], w5=p[t+5], w6=p[t+6],
          w7=p[t+7], w8=p[t+8], w9=p[t+9], w10=p[t+10], w11=p[t+11], w12=p[t+12], w13=p[t+13], w14;
    float a0=0.f,a1=0.f,a2=0.f,a3=0.f,a4=0.f,a5=0.f,a6=0.f,a7=0.f,a8=0.f,a9=0.f,
          a10=0.f,a11=0.f,a12=0.f,a13=0.f,a14=0.f, s1=0.f;
    #define ASTEP(wA,wB,wC,wD,wE,wF,wG,wH,wI,wJ,wK,wL,wM,wN,wO, off) { \
        wO = p[t + (off) + 14]; \
        s1 += wA; \
        a0  = fmaf(wA,wA,a0);  a1  = fmaf(wA,wB,a1);  a2  = fmaf(wA,wC,a2);  \
        a3  = fmaf(wA,wD,a3);  a4  = fmaf(wA,wE,a4);  a5  = fmaf(wA,wF,a5);  \
        a6  = fmaf(wA,wG,a6);  a7  = fmaf(wA,wH,a7);  a8  = fmaf(wA,wI,a8);  \
        a9  = fmaf(wA,wJ,a9);  a10 = fmaf(wA,wK,a10); a11 = fmaf(wA,wL,a11); \
        a12 = fmaf(wA,wM,a12); a13 = fmaf(wA,wN,a13); a14 = fmaf(wA,wO,a14); }
    #define AR0(o)  ASTEP(w0,w1,w2,w3,w4,w5,w6,w7,w8,w9,w10,w11,w12,w13,w14, o)
    #define AR1(o)  ASTEP(w1,w2,w3,w4,w5,w6,w7,w8,w9,w10,w11,w12,w13,w14,w0, o)
    #define AR2(o)  ASTEP(w2,w3,w4,w5,w6,w7,w8,w9,w10,w11,w12,w13,w14,w0,w1, o)
    #define AR3(o)  ASTEP(w3,w4,w5,w6,w7,w8,w9,w10,w11,w12,w13,w14,w0,w1,w2, o)
    #define AR4(o)  ASTEP(w4,w5,w6,w7,w8,w9,w10,w11,w12,w13,w14,w0,w1,w2,w3, o)
    #define AR5(o)  ASTEP(w5,w6,w7,w8,w9,w10,w11,w12,w13,w14,w0,w1,w2,w3,w4, o)
    #define AR6(o)  ASTEP(w6,w7,w8,w9,w10,w11,w12,w13,w14,w0,w1,w2,w3,w4,w5, o)
    #define AR7(o)  ASTEP(w7,w8,w9,w10,w11,w12,w13,w14,w0,w1,w2,w3,w4,w5,w6, o)
    #define AR8(o)  ASTEP(w8,w9,w10,w11,w12,w13,w14,w0,w1,w2,w3,w4,w5,w6,w7, o)
    #define AR9(o)  ASTEP(w9,w10,w11,w12,w13,w14,w0,w1,w2,w3,w4,w5,w6,w7,w8, o)
    #define AR10(o) ASTEP(w10,w11,w12,w13,w14,w0,w1,w2,w3,w4,w5,w6,w7,w8,w9, o)
    #define AR11(o) ASTEP(w11,w12,w13,w14,w0,w1,w2,w3,w4,w5,w6,w7,w8,w9,w10, o)
    #define AR12(o) ASTEP(w12,w13,w14,w0,w1,w2,w3,w4,w5,w6,w7,w8,w9,w10,w11, o)
    #define AR13(o) ASTEP(w13,w14,w0,w1,w2,w3,w4,w5,w6,w7,w8,w9,w10,w11,w12, o)
    #define AR14(o) ASTEP(w14,w0,w1,w2,w3,w4,w5,w6,w7,w8,w9,w10,w11,w12,w13, o)
    for (int mi = 0; mi < 2; ++mi) {
        AR0(0) AR1(1) AR2(2) AR3(3) AR4(4) AR5(5) AR6(6) AR7(7)
        AR8(8) AR9(9) AR10(10) AR11(11) AR12(12) AR13(13) AR14(14)
        t += 15;
    }
    AR0(0) AR1(1) AR2(2)                        // 33 total
    #undef ASTEP
    __syncthreads();
    float eacc = 0.f;
    int v = threadIdx.x;
    if (v < 147) {
        int mode, ia, ib;
        if (v < 105) { mode = 0; ia = v / 15; ib = ia + (v % 15); }
        else if (v < 133) {
            int idx = v - 105; int i = 0, len = 7;
            while (idx >= len) { idx -= len; ++i; --len; }
            mode = 2; ia = 993 + i; ib = 993 + i + idx;
        }
        else if (v < 140) { mode = 1; ia = 0; ib = v - 133; }
        else { mode = 1; ia = 993 + (v - 140); ib = 999; }
        for (int rr = 0; rr < 8; ++rr) {
            const float* zr = &rows[rr][0];
            float val;
            if (mode != 1) val = zr[ia] * zr[ib];
            else { val = 0.f; for (int i = ia; i <= ib; ++i) val += zr[i]; }
            eacc += val;
        }
    }
    __syncthreads();
    float* red = &rows[0][0];
    int tid = threadIdx.x;
    red[tid*17+0]=a0;  red[tid*17+1]=a1;  red[tid*17+2]=a2;  red[tid*17+3]=a3;
    red[tid*17+4]=a4;  red[tid*17+5]=a5;  red[tid*17+6]=a6;  red[tid*17+7]=a7;
    red[tid*17+8]=a8;  red[tid*17+9]=a9;  red[tid*17+10]=a10; red[tid*17+11]=a11;
    red[tid*17+12]=a12; red[tid*17+13]=a13; red[tid*17+14]=a14; red[tid*17+15]=s1;
    __syncthreads();
    for (int off = 128; off > 0; off >>= 1) {
        if (tid < off)
            for (int k = 0; k < 16; ++k) red[tid*17+k] += red[(tid+off)*17+k];
        __syncthreads();
    }
    if (tid < 16) atomicAdd(&stats[tid], (double)red[tid]);
    if (v < 147) atomicAdd(&stats[16 + v], (double)eacc);
}

// ---- E: finalize BN (parallel: 256 threads, stats in LDS) -> folded taps ----
__global__ __launch_bounds__(256) void k_finalize2(const double* __restrict__ stats,
                            const float* __restrict__ conv_w,
                            const float* __restrict__ gamma, const float* __restrict__ beta,
                            float* __restrict__ scsh) {
    __shared__ double sst[163];
    __shared__ double pd[16][16];
    int tid = threadIdx.x;
    if (tid < 163) sst[tid] = stats[tid];
    __syncthreads();
    int h = tid >> 4, j = tid & 15;
    const double SA = sst[15];
    const double* HP  = sst + 16;
    const double* TP  = sst + 16 + 105;
    const double* PRE = sst + 16 + 133;
    const double* SUF = sst + 16 + 140;
    double w[15];
    #pragma unroll
    for (int k = 0; k < 15; ++k) w[k] = (double)conv_w[h * 15 + k];
    double part = 0.0;
    if (j < 15) {                               // k = j slice of the quadratic form
        int k = j;
        #pragma unroll
        for (int k2 = 0; k2 < 15; ++k2) {
            int a = (k < k2) ? k : k2;
            int d = (k < k2) ? (k2 - k) : (k - k2);
            double G = sst[d];
            if (a >= 8)
                for (int i = 0; i <= a - 8; ++i) G -= HP[i * 15 + d];
            if (a + d <= 6)
                for (int i = a + 993; i <= 999 - d; ++i) {
                    int ip = i - 993;
                    G -= TP[ip * 7 - ip * (ip - 1) / 2 + d];
                }
            part += w[k] * w[k2] * G;
        }
    } else {                                    // j == 15: mean numerator
        double so = 0.0;
        #pragma unroll
        for (int k = 0; k < 15; ++k) {
            double U = SA;
            if (k < 7)      U -= SUF[k];
            else if (k > 7) U -= PRE[k - 8];
            so += w[k] * U;
        }
        part = so;
    }
    pd[h][j] = part;
    __syncthreads();
    if (j == 0) {
        const double M = (double)(B_ * N_) * (double)T_;
        double q = 0.0;
        #pragma unroll
        for (int jj = 0; jj < 15; ++jj) q += pd[h][jj];
        double mean_o = pd[h][15] / M;
        double var = q / M - mean_o * mean_o;
        double sc = (double)gamma[h] / sqrt(var + 1e-5);
        scsh[240 + h] = (float)((double)beta[h] - mean_o * sc);
        #pragma unroll
        for (int k = 0; k < 15; ++k) scsh[h * 15 + k] = (float)(w[k] * sc);
    }
}

// ------- F: conv via packed pairs + ELU + serial LIF, BARRIER-FREE ---------
// 4 independent waves per block; each wave owns 4 rows x 16 ch and its own
// LDS slice (dual-copy for aligned b64 O-pairs). No __syncthreads at all:
// wave-private LDS needs only the compiler's lgkmcnt waits.
__global__ __launch_bounds__(256, 2) void k_scan(const float* __restrict__ zg,
        const float* __restrict__ scsh, float* __restrict__ zfeat) {
    __shared__ float in_s[4][2][4][68];
    __shared__ float in2[4][2][4][68];
    int tid = threadIdx.x;
    int wv = tid >> 6, lane = tid & 63;
    int h = lane & 15, rl = lane >> 4;          // row-in-wave 0..3
    int row0 = blockIdx.x * 16 + wv * 4;        // this wave's 4 rows
    float c0 = scsh[h*15+0],  c1 = scsh[h*15+1],  c2 = scsh[h*15+2],  c3 = scsh[h*15+3];
    float c4 = scsh[h*15+4],  c5 = scsh[h*15+5],  c6 = scsh[h*15+6],  c7 = scsh[h*15+7];
    float c8 = scsh[h*15+8],  c9 = scsh[h*15+9],  c10 = scsh[h*15+10], c11 = scsh[h*15+11];
    float c12 = scsh[h*15+12], c13 = scsh[h*15+13], c14 = scsh[h*15+14];
    float sh = scsh[240 + h];
    v2f cb0 = {c0,c0},  cb1 = {c1,c1},  cb2 = {c2,c2},  cb3 = {c3,c3},  cb4 = {c4,c4};
    v2f cb5 = {c5,c5},  cb6 = {c6,c6},  cb7 = {c7,c7},  cb8 = {c8,c8},  cb9 = {c9,c9};
    v2f cb10 = {c10,c10}, cb11 = {c11,c11}, cb12 = {c12,c12}, cb13 = {c13,c13}, cb14 = {c14,c14};
    v2f shp = {sh, sh}, zzp = {0.f, 0.f};
    float u = 2.f, cnt = 0.f;
    float ld0, ld1, ld2, ld3;

    #define STAGE_LOAD(cc) { \
        int g = (cc) * 48 - 7 + lane; \
        bool ok = (g >= 0 && g < T_); \
        const float* zp_ = zg + (size_t)row0 * T_ + g; \
        ld0 = ok ? zp_[0] : 0.f; \
        ld1 = ok ? zp_[T_] : 0.f; \
        ld2 = ok ? zp_[2 * T_] : 0.f; \
        ld3 = ok ? zp_[3 * T_] : 0.f; }

    #define STAGE_WRITE(db) { \
        in_s[wv][db][0][lane] = ld0;  in2[wv][db][0][lane + 1] = ld0; \
        in_s[wv][db][1][lane] = ld1;  in2[wv][db][1][lane + 1] = ld1; \
        in_s[wv][db][2][lane] = ld2;  in2[wv][db][2][lane + 1] = ld2; \
        in_s[wv][db][3][lane] = ld3;  in2[wv][db][3][lane + 1] = ld3; }

    #define PK_FMA(acc, c, xp) asm("v_pk_fma_f32 %0, %1, %2, %0" : "+v"(acc) : "v"(c), "v"(xp))
    #define PK_ADD(d, a, b)    asm("v_pk_add_f32 %0, %1, %2" : "=v"(d) : "v"(a), "v"(b))

    #define LIF1(aa) { \
        u = fmaf(0.5f, u, aa); \
        float sp = (u > 2.5f) ? 1.f : 0.f; \
        cnt += sp; u = fmaf(-0.5f, sp, u); }

    #define PAIR(Ea,Eb,Ec,Ed,Ee,Ef,Eg,Eh, Oa,Ob,Oc,Od,Oe,Of,Og) { \
        v2f aE = shp, aO = zzp; \
        PK_FMA(aE, cb0,  Ea); PK_FMA(aO, cb1,  Oa); \
        PK_FMA(aE, cb2,  Eb); PK_FMA(aO, cb3,  Ob); \
        PK_FMA(aE, cb4,  Ec); PK_FMA(aO, cb5,  Oc); \
        PK_FMA(aE, cb6,  Ed); PK_FMA(aO, cb7,  Od); \
        PK_FMA(aE, cb8,  Ee); PK_FMA(aO, cb9,  Oe); \
        PK_FMA(aE, cb10, Ef); PK_FMA(aO, cb11, Of); \
        PK_FMA(aE, cb12, Eg); PK_FMA(aO, cb13, Og); \
        PK_FMA(aE, cb14, Eh); \
        v2f zp; PK_ADD(zp, aE, aO); \
        float pe0 = fmaxf(zp.x, 0.f) + __expf(fminf(zp.x, 0.f)); \
        float pe1 = fmaxf(zp.y, 0.f) + __expf(fminf(zp.y, 0.f)); \
        LIF1(pe0) LIF1(pe1) }

    // E_j = (z[2j], z[2j+1]) at in_s offset 2j (8B aligned);
    // O_j = (z[2j+1], z[2j+2]) at in2 offset 2j+2 (8B aligned).
    #define LDE(j) (*(const v2f*)(pN + 2*(j)))
    #define LDO(j) (*(const v2f*)(p2 + 2*(j) + 2))
    #define LOADWIN \
        v2f E0=LDE(0),  E1=LDE(1),  E2=LDE(2),  E3=LDE(3),  E4=LDE(4),  E5=LDE(5),  E6=LDE(6),  E7=LDE(7), \
            E8=LDE(8),  E9=LDE(9),  E10=LDE(10), E11=LDE(11), E12=LDE(12), E13=LDE(13), E14=LDE(14), E15=LDE(15), \
            E16=LDE(16), E17=LDE(17), E18=LDE(18), E19=LDE(19), E20=LDE(20), E21=LDE(21), E22=LDE(22), E23=LDE(23), \
            E24=LDE(24), E25=LDE(25), E26=LDE(26), E27=LDE(27), E28=LDE(28), E29=LDE(29), E30=LDE(30); \
        v2f O0=LDO(0),  O1=LDO(1),  O2=LDO(2),  O3=LDO(3),  O4=LDO(4),  O5=LDO(5),  O6=LDO(6),  O7=LDO(7), \
            O8=LDO(8),  O9=LDO(9),  O10=LDO(10), O11=LDO(11), O12=LDO(12), O13=LDO(13), O14=LDO(14), O15=LDO(15), \
            O16=LDO(16), O17=LDO(17), O18=LDO(18), O19=LDO(19), O20=LDO(20), O21=LDO(21), O22=LDO(22), O23=LDO(23), \
            O24=LDO(24), O25=LDO(25), O26=LDO(26), O27=LDO(27), O28=LDO(28), O29=LDO(29);

    #define PAIRS20 \
        PAIR(E0,E1,E2,E3,E4,E5,E6,E7,       O0,O1,O2,O3,O4,O5,O6) \
        PAIR(E1,E2,E3,E4,E5,E6,E7,E8,       O1,O2,O3,O4,O5,O6,O7) \
        PAIR(E2,E3,E4,E5,E6,E7,E8,E9,       O2,O3,O4,O5,O6,O7,O8) \
        PAIR(E3,E4,E5,E6,E7,E8,E9,E10,      O3,O4,O5,O6,O7,O8,O9) \
        PAIR(E4,E5,E6,E7,E8,E9,E10,E11,     O4,O5,O6,O7,O8,O9,O10) \
        PAIR(E5,E6,E7,E8,E9,E10,E11,E12,    O5,O6,O7,O8,O9,O10,O11) \
        PAIR(E6,E7,E8,E9,E10,E11,E12,E13,   O6,O7,O8,O9,O10,O11,O12) \
        PAIR(E7,E8,E9,E10,E11,E12,E13,E14,  O7,O8,O9,O10,O11,O12,O13) \
        PAIR(E8,E9,E10,E11,E12,E13,E14,E15, O8,O9,O10,O11,O12,O13,O14) \
        PAIR(E9,E10,E11,E12,E13,E14,E15,E16, O9,O10,O11,O12,O13,O14,O15) \
        PAIR(E10,E11,E12,E13,E14,E15,E16,E17, O10,O11,O12,O13,O14,O15,O16) \
        PAIR(E11,E12,E13,E14,E15,E16,E17,E18, O11,O12,O13,O14,O15,O16,O17) \
        PAIR(E12,E13,E14,E15,E16,E17,E18,E19, O12,O13,O14,O15,O16,O17,O18) \
        PAIR(E13,E14,E15,E16,E17,E18,E19,E20, O13,O14,O15,O16,O17,O18,O19) \
        PAIR(E14,E15,E16,E17,E18,E19,E20,E21, O14,O15,O16,O17,O18,O19,O20) \
        PAIR(E15,E16,E17,E18,E19,E20,E21,E22, O15,O16,O17,O18,O19,O20,O21) \
        PAIR(E16,E17,E18,E19,E20,E21,E22,E23, O16,O17,O18,O19,O20,O21,O22) \
        PAIR(E17,E18,E19,E20,E21,E22,E23,E24, O17,O18,O19,O20,O21,O22,O23) \
        PAIR(E18,E19,E20,E21,E22,E23,E24,E25, O18,O19,O20,O21,O22,O23,O24) \
        PAIR(E19,E20,E21,E22,E23,E24,E25,E26, O19,O20,O21,O22,O23,O24,O25)

    #define PAIRS_LAST4 \
        PAIR(E20,E21,E22,E23,E24,E25,E26,E27, O20,O21,O22,O23,O24,O25,O26) \
        PAIR(E21,E22,E23,E24,E25,E26,E27,E28, O21,O22,O23,O24,O25,O26,O27) \
        PAIR(E22,E23,E24,E25,E26,E27,E28,E29, O22,O23,O24,O25,O26,O27,O28) \
        PAIR(E23,E24,E25,E26,E27,E28,E29,E30, O23,O24,O25,O26,O27,O28,O29)

    STAGE_LOAD(0)
    STAGE_WRITE(0)
    int buf = 0;
    #pragma unroll 1
    for (int c = 0; c < 20; ++c) {
        STAGE_LOAD(c + 1)                       // issue early (T14)
        {
            const float* pN = &in_s[wv][buf][rl][0];
            const float* p2 = &in2[wv][buf][rl][0];
            LOADWIN
            PAIRS20
            PAIRS_LAST4
        }
        STAGE_WRITE(buf ^ 1)                    // write late (after compute)
        buf ^= 1;
    }
    {   // tail chunk: 40 outputs = 20 pairs
        const float* pN = &in_s[wv][buf][rl][0];
        const float* p2 = &in2[wv][buf][rl][0];
        LOADWIN
        PAIRS20
    }
    #undef STAGE_LOAD
    #undef STAGE_WRITE
    #undef PK_FMA
    #undef PK_ADD
    #undef LIF1
    #undef PAIR
    #undef LDE
    #undef LDO
    #undef LOADWIN
    #undef PAIRS20
    #undef PAIRS_LAST4
    int row = row0 + rl;
    int b = row >> 6, i = row & 63;
    zfeat[(size_t)b * 1024 + h * 64 + i] = cnt * (1.0f / (float)T_);
}

// ---------------- G: logits = z_feat @ fc_w.T + fc_b -----------------------
__global__ __launch_bounds__(256) void k_fc(const float* __restrict__ zfeat, const float* __restrict__ fc_w,
                     const float* __restrict__ fc_b, float* __restrict__ logits) {
    int b = blockIdx.x;
    const float* zf = zfeat + (size_t)b * 1024;
    float a0 = 0.f, a1 = 0.f, a2 = 0.f, a3 = 0.f;
    for (int f = threadIdx.x; f < 1024; f += 256) {
        float z = zf[f];
        a0 += z * fc_w[f];
        a1 += z * fc_w[1024 + f];
        a2 += z * fc_w[2048 + f];
        a3 += z * fc_w[3072 + f];
    }
    __shared__ float red[4][256];
    red[0][threadIdx.x] = a0; red[1][threadIdx.x] = a1;
    red[2][threadIdx.x] = a2; red[3][threadIdx.x] = a3;
    __syncthreads();
    for (int off = 128; off > 0; off >>= 1) {
        if (threadIdx.x < off) {
            red[0][threadIdx.x] += red[0][threadIdx.x + off];
            red[1][threadIdx.x] += red[1][threadIdx.x + off];
            red[2][threadIdx.x] += red[2][threadIdx.x + off];
            red[3][threadIdx.x] += red[3][threadIdx.x + off];
        }
        __syncthreads();
    }
    if (threadIdx.x < 4) logits[b * 4 + threadIdx.x] = red[threadIdx.x][0] + fc_b[threadIdx.x];
}

extern "C" void kernel_launch(void* const* d_in, const int* in_sizes, int n_in,
                              void* d_out, int out_size, void* d_ws, size_t ws_size,
                              hipStream_t stream) {
    (void)in_sizes; (void)n_in; (void)out_size; (void)ws_size;
    const float* x      = (const float*)d_in[0];
    const float* q_w    = (const float*)d_in[1];
    const float* q_b    = (const float*)d_in[2];
    const float* k_w    = (const float*)d_in[3];
    const float* k_b    = (const float*)d_in[4];
    const float* conv_w = (const float*)d_in[5];
    const float* bn_g   = (const float*)d_in[7];
    const float* bn_b   = (const float*)d_in[8];
    const float* fc_w   = (const float*)d_in[9];
    const float* fc_b   = (const float*)d_in[10];

    float* out    = (float*)d_out;
    float* logits = out;                        // 128*4
    float* zfeat  = out + 512;                  // 128*1024
    float* wmat   = out + 512 + 131072;         // 128*64*64

    char* ws      = (char*)d_ws;
    float* energy = (float*)ws;                               // 32 KB
    float* zg     = (float*)(ws + 32768);                     // 32.768 MB
    double* stats = (double*)(ws + 32768 + 32768000);         // 2 KB
    float* scsh   = (float*)(ws + 32768 + 32768000 + 2048);   // 1 KB

    k_energy<<<B_ * N_, 256, 0, stream>>>(x, energy);
    k_zgcn<<<dim3(8, B_), 256, 0, stream>>>(energy, q_w, q_b, k_w, k_b, x, zg, wmat, stats);
    k_autocorr<<<B_ * N_ / 8, 256, 0, stream>>>(zg, stats);
    k_finalize2<<<1, 256, 0, stream>>>(stats, conv_w, bn_g, bn_b, scsh);
    k_scan<<<B_ * N_ / 16, 256, 0, stream>>>(zg, scsh, zfeat);
    k_fc<<<B_, 256, 0, stream>>>(zfeat, fc_w, fc_b, logits);
}